// Round 2
// baseline (10141.598 us; speedup 1.0000x reference)
//
#include <hip/hip_runtime.h>
#include <math.h>

#define T_ 32
#define B_ 16
#define NA 18
#define P_ 540   // 27*20

typedef __attribute__((ext_vector_type(8)))  short short8;
typedef __attribute__((ext_vector_type(16))) float f32x16;

__device__ __forceinline__ float sigm(float x){ return 1.0f/(1.0f+expf(-x)); }
__device__ __forceinline__ unsigned short f2bf(float f){
    unsigned u = __float_as_uint(f);
    u += 0x7fff + ((u>>16)&1u);
    return (unsigned short)(u>>16);
}
__device__ __forceinline__ float bfu(unsigned short u){ return __uint_as_float(((unsigned)u)<<16); }

// ---------------- conv1: (512,3,210,160) -> c1pad bf16 [512][32][56][42], k8 s4 padH(1,1) W(2,2)
__global__ __launch_bounds__(256) void conv1k(const float* __restrict__ frame,
                                              const float* __restrict__ w,
                                              const float* __restrict__ bias,
                                              unsigned short* __restrict__ c1pad){
    __shared__ float tile[4032];  // 3ch * 8rows * 168cols (padded)
    int bid = blockIdx.x;
    int n = bid / 52, oh = bid % 52;
    int tid = threadIdx.x;
    const float* fb = frame + (size_t)n*3*210*160;
    for (int s = tid; s < 4032; s += 256){
        int col = s % 168;
        int row = (s/168) & 7;
        int ic  = s / 1344;
        int iy = oh*4 - 1 + row;
        int ix = col - 2;
        float v = 0.f;
        if (iy >= 0 && iy < 210 && ix >= 0 && ix < 160) v = fb[ic*33600 + iy*160 + ix];
        tile[s] = v;
    }
    __syncthreads();
    int oc = tid & 31, grp = tid >> 5;      // grp 0..7 -> ow = grp*5..grp*5+4
    float acc[5] = {0.f,0.f,0.f,0.f,0.f};
    const float* wb = w + oc*192;
    for (int ic=0; ic<3; ++ic){
        #pragma unroll
        for (int kh=0; kh<8; ++kh){
            const float* wr = wb + ic*64 + kh*8;
            float4 w0 = *((const float4*)wr);
            float4 w1 = *((const float4*)(wr+4));
            const float* row = tile + ic*1344 + kh*168 + grp*20;
            float r[24];
            *((float4*)(r+ 0)) = *((const float4*)(row+ 0));
            *((float4*)(r+ 4)) = *((const float4*)(row+ 4));
            *((float4*)(r+ 8)) = *((const float4*)(row+ 8));
            *((float4*)(r+12)) = *((const float4*)(row+12));
            *((float4*)(r+16)) = *((const float4*)(row+16));
            *((float4*)(r+20)) = *((const float4*)(row+20));
            #pragma unroll
            for (int o=0;o<5;++o){
                acc[o] += r[o*4+0]*w0.x + r[o*4+1]*w0.y + r[o*4+2]*w0.z + r[o*4+3]*w0.w
                        + r[o*4+4]*w1.x + r[o*4+5]*w1.y + r[o*4+6]*w1.z + r[o*4+7]*w1.w;
            }
        }
    }
    float bi = bias[oc];
    unsigned short* ob = c1pad + ((size_t)(n*32 + oc)*56 + oh+2)*42 + 1;
    #pragma unroll
    for (int o=0;o<5;++o) ob[grp*5+o] = f2bf(acc[o] + bi);
}

// ---------------- conv2 A-pack: cnn_w2 (64,32,4,4) -> apack2[32 ic][2 mt][64 lane][8] bf16
__global__ void apack2k(const float* __restrict__ w2, unsigned short* __restrict__ ap){
    int idx = blockIdx.x*256 + threadIdx.x;
    if (idx >= 32768) return;
    int j = idx & 7;
    int lane = (idx>>3) & 63;
    int mt = (idx>>9) & 1;
    int ic = idx >> 10;
    int k = ((lane>>5)<<3) + j;          // kh*4+kw
    int oc = mt*32 + (lane & 31);
    ap[idx] = f2bf(w2[((oc*32 + ic)<<4) + k]);
}

// ---------------- conv2 MFMA: c1pad bf16 -> xpad bf16 [512][64][640], k4 s2 padH(2,2) W(1,1)
__global__ __launch_bounds__(256) void c2mfma(const unsigned short* __restrict__ c1pad,
                                              const unsigned short* __restrict__ apack2,
                                              const float* __restrict__ bias,
                                              unsigned short* __restrict__ xpad){
    __shared__ unsigned short p2[2][3072];   // [n 128][stride 24]
    __shared__ float bsm[64];
    int bid = blockIdx.x;
    int s = bid / 5;
    int n0 = (bid % 5) * 128;
    int tid = threadIdx.x;
    int wave = tid >> 6, lane = tid & 63;
    int khalf = (lane>>5) << 3;
    if (tid < 64) bsm[tid] = bias[tid];
    const unsigned short* cb = c1pad + (size_t)s*32*2352;

    int soff[8], swaddr[8];
    #pragma unroll
    for (int q=0;q<8;++q){
        int idx = q*256 + tid;
        int n = idx & 127, k = idx >> 7;
        int p = n0 + n; if (p > 539) p = 539;
        soff[q] = ((p/20)*2 + (k>>2))*42 + (p%20)*2 + (k&3);
        swaddr[q] = n*24 + k;
    }
    #pragma unroll
    for (int q=0;q<8;++q) p2[0][swaddr[q]] = cb[soff[q]];
    unsigned short rv[8];
    #pragma unroll
    for (int q=0;q<8;++q) rv[q] = cb[2352 + soff[q]];

    int mt = wave >> 1, ntb = (wave & 1) * 2;
    short8 acur = *((const short8*)(apack2 + ((size_t)mt*64 + lane)*8));
    short8 anxt;
    f32x16 acc[2];
    #pragma unroll
    for (int jj=0;jj<2;++jj)
        #pragma unroll
        for (int rg=0;rg<16;++rg) acc[jj][rg] = 0.f;
    __syncthreads();

    for (int c=0; c<32; ++c){
        int buf = c & 1;
        if (c < 31){
            #pragma unroll
            for (int q=0;q<8;++q) p2[buf^1][swaddr[q]] = rv[q];
        }
        if (c < 30){
            const unsigned short* src = cb + (size_t)(c+2)*2352;
            #pragma unroll
            for (int q=0;q<8;++q) rv[q] = src[soff[q]];
        }
        if (c < 31) anxt = *((const short8*)(apack2 + ((size_t)((c+1)*2 + mt)*64 + lane)*8));
        #pragma unroll
        for (int jj=0;jj<2;++jj){
            int n = (ntb+jj)*32 + (lane & 31);
            short8 bf = *((const short8*)(&p2[buf][n*24 + khalf]));
            acc[jj] = __builtin_amdgcn_mfma_f32_32x32x16_bf16(acur, bf, acc[jj], 0, 0, 0);
        }
        acur = anxt;
        __syncthreads();
    }
    #pragma unroll
    for (int jj=0;jj<2;++jj){
        int pos = n0 + (ntb+jj)*32 + (lane & 31);
        if (pos >= 540) continue;
        int y = pos/20, x = pos%20;
        unsigned short* op = xpad + (size_t)s*64*640 + (y+1)*22 + x + 1;
        #pragma unroll
        for (int rg=0; rg<16; ++rg){
            int oc = mt*32 + (rg & 3) + 8*(rg>>2) + 4*(lane>>5);
            op[(size_t)oc*640] = f2bf(acc[jj][rg] + bsm[oc]);
        }
    }
}

// ---------------- spatial basis S[540][64]
__global__ void sbasisk(float* __restrict__ S){
    int idx = blockIdx.x*256 + threadIdx.x;
    if (idx >= P_*64) return;
    int s = idx & 63, p = idx >> 6;
    int y = p/20, x = p%20;
    int u = s >> 3, v = s & 7;
    double a  = cos((double)((y+1)*(u+1)) * M_PI / 27.0);
    double bb = cos((double)((x+1)*(v+1)) * M_PI / 20.0);
    S[idx] = (float)(a*bb);
}

// ---------------- weight pack: f32 [R][C] -> bf16 [(R+3)/4][C][4]  (pad rows -> 0)
__global__ void packw4k(const float* __restrict__ in, unsigned short* __restrict__ out, int R, int C){
    int idx = blockIdx.x*256 + threadIdx.x;
    int r4cnt = (R+3)>>2;
    if (idx >= r4cnt*C*4) return;
    int j = idx & 3;
    int rc = idx >> 2;
    int c = rc % C;
    int r = (rc / C)*4 + j;
    out[idx] = (r < R) ? f2bf(in[(size_t)r*C + c]) : (unsigned short)0;
}
// ---------------- weight pack (transposed input): f32 [C][R] -> bf16 [(R+3)/4][C][4]
__global__ void packt4k(const float* __restrict__ in, unsigned short* __restrict__ out, int R, int C){
    int idx = blockIdx.x*256 + threadIdx.x;
    int r4cnt = (R+3)>>2;
    if (idx >= r4cnt*C*4) return;
    int j = idx & 3;
    int rc = idx >> 2;
    int c = rc % C;
    int r = (rc / C)*4 + j;
    out[idx] = (r < R) ? f2bf(in[(size_t)c*R + r]) : (unsigned short)0;
}

// ---------------- gates A-pack: lstm_w (512,192,3,3) -> apack[192][16][64][8] bf16 (k>=9 -> 0)
__global__ void apackk(const float* __restrict__ lw, unsigned short* __restrict__ ap){
    int idx = blockIdx.x*256 + threadIdx.x;
    if (idx >= 1572864) return;
    int j = idx & 7;
    int lane = (idx>>3) & 63;
    int mt = (idx>>9) & 15;
    int ch = idx >> 13;
    int kk = ((lane>>5)<<3) + j;
    int oc = mt*32 + (lane & 31);
    ap[idx] = (kk < 9) ? f2bf(lw[(size_t)oc*1728 + ch*9 + kk]) : (unsigned short)0;
}

// ---------------- pack conv_h0 fp32 -> hpad bf16 interior
__global__ void h0packk(const float* __restrict__ h0, unsigned short* __restrict__ hpad){
    int idx = blockIdx.x*256 + threadIdx.x;
    if (idx >= 16*128*540) return;
    int plane = idx / 540, p = idx % 540;
    hpad[(size_t)plane*640 + (p/20+1)*22 + (p%20) + 1] = f2bf(h0[idx]);
}

// ---------------- fused gates GEMM + vis-LSTM pointwise.
// grid 288 = 16b * 9nb * 2mh ; 256 thr = 4 waves.  wave w owns GATE w (i/f/o/g) for the
// block's 64 channels x 64 positions: mt = wave*4 + mh*2 + i.  Gates staged in LDS
// (overlaid on the K-loop panel), LSTM pointwise fused in epilogue: no gates HBM
// round-trip, no separate vupdk dispatch.  hpad double-buffered (hrd read / hwr write).
__global__ __launch_bounds__(256) void gvk(const unsigned short* __restrict__ xpad,
                                           const unsigned short* __restrict__ hrd,
                                           unsigned short* __restrict__ hwr,
                                           const unsigned short* __restrict__ apack,
                                           const float* __restrict__ lb,
                                           const unsigned char* __restrict__ done,
                                           float* __restrict__ vh, float* __restrict__ vc,
                                           unsigned short* __restrict__ hreA, int t){
    __shared__ __align__(16) unsigned char smraw[65536];
    unsigned short (*panel)[6144] = (unsigned short (*)[6144])smraw;  // [2][6144] = 24.5 KB
    float* gsm = (float*)smraw;                                       // [4][64][64] f32 = 64 KB (after loop)
    int bid = blockIdx.x;
    int b  = bid % 16;
    int r  = bid / 16;
    int nb = r % 9;
    int mh = r / 9;
    int tid = threadIdx.x;
    int wave = tid >> 6, lane = tid & 63;
    int khalf = (lane>>5) << 3;
    int n0 = nb * 64;
    bool dn = done[t*B_ + b];

    const unsigned short* xb = xpad + ((size_t)(t*B_ + b))*64*640;
    const unsigned short* hb = hrd + (size_t)b*128*640;

    int soff[9], swaddr[9], gq[9];
    #pragma unroll
    for (int q=0;q<9;++q){
        int idx = q*256 + tid;
        int g = idx / 576;
        int rr = idx % 576;
        int k = rr / 64, n = rr & 63;
        int p = n0 + n; if (p > 539) p = 539;
        int pbase = (p/20)*22 + (p%20);
        soff[q] = pbase + (k/3)*22 + (k%3);
        swaddr[q] = g*1536 + n*24 + k;
        gq[q] = g;
    }
    // zero padding k-rows 9..15 of both buffers
    for (int s2 = tid; s2 < 3584; s2 += 256){
        int bf2 = s2 / 1792, r2 = s2 % 1792;
        int g2 = r2 / 448, rr2 = r2 % 448;
        panel[bf2][g2*1536 + (rr2 & 63)*24 + 9 + (rr2>>6)] = 0;
    }
    #pragma unroll
    for (int q=0;q<9;++q) panel[0][swaddr[q]] = xb[gq[q]*640 + soff[q]];
    unsigned short rv[9];
    #pragma unroll
    for (int q=0;q<9;++q) rv[q] = xb[(4+gq[q])*640 + soff[q]];

    short8 acur[4][2], anxt[4][2];
    #pragma unroll
    for (int g=0;g<4;++g)
        #pragma unroll
        for (int i=0;i<2;++i){
            int mt = wave*4 + mh*2 + i;      // wave = gate index
            acur[g][i] = *((const short8*)(apack + ((size_t)(g*16 + mt)*64 + lane)*8));
        }

    f32x16 acc[2][2];
    #pragma unroll
    for (int j=0;j<2;++j)
        #pragma unroll
        for (int i=0;i<2;++i)
            #pragma unroll
            for (int rg=0;rg<16;++rg) acc[j][i][rg] = 0.f;

    __syncthreads();

    for (int it=0; it<48; ++it){
        int buf = it & 1;
        if (it < 47){
            #pragma unroll
            for (int q=0;q<9;++q) panel[buf^1][swaddr[q]] = rv[q];
        }
        if (it < 46){
            int icb = (it+2)*4;
            #pragma unroll
            for (int q=0;q<9;++q){
                int ic = icb + gq[q];
                rv[q] = (ic < 64) ? xb[ic*640 + soff[q]]
                                  : (dn ? (unsigned short)0 : hb[(ic-64)*640 + soff[q]]);
            }
        }
        if (it < 47){
            int cb2 = (it+1)*4;
            #pragma unroll
            for (int g=0;g<4;++g)
                #pragma unroll
                for (int i=0;i<2;++i){
                    int mt = wave*4 + mh*2 + i;
                    anxt[g][i] = *((const short8*)(apack + ((size_t)((cb2+g)*16 + mt)*64 + lane)*8));
                }
        }
        #pragma unroll
        for (int g=0;g<4;++g){
            #pragma unroll
            for (int j=0;j<2;++j){
                int n = j*32 + (lane & 31);
                short8 bf = *((const short8*)(&panel[buf][g*1536 + n*24 + khalf]));
                #pragma unroll
                for (int i=0;i<2;++i)
                    acc[j][i] = __builtin_amdgcn_mfma_f32_32x32x16_bf16(acur[g][i], bf, acc[j][i], 0, 0, 0);
            }
        }
        #pragma unroll
        for (int g=0;g<4;++g){ acur[g][0] = anxt[g][0]; acur[g][1] = anxt[g][1]; }
        __syncthreads();
    }

    // stage gates to LDS: gsm[wave][c_loc][p_loc]
    #pragma unroll
    for (int j=0;j<2;++j){
        int p_loc = j*32 + (lane & 31);
        #pragma unroll
        for (int i=0;i<2;++i){
            #pragma unroll
            for (int rg=0; rg<16; ++rg){
                int c_loc = i*32 + 4*(lane>>5) + (rg & 3) + 8*(rg>>2);
                gsm[wave*4096 + c_loc*64 + p_loc] = acc[j][i][rg];
            }
        }
    }
    __syncthreads();

    // fused LSTM pointwise: 256 threads x 16 elements over 64c x 64p
    {
        int p_loc = tid & 63, c0 = tid >> 6;
        int pg = n0 + p_loc;
        if (pg < 540){
            float m = dn ? 0.f : 1.f;
            int y = pg/20, x = pg%20;
            #pragma unroll
            for (int e=0;e<16;++e){
                int c_loc = c0*16 + e;
                int cg = mh*64 + c_loc;
                float gi = gsm[        c_loc*64 + p_loc] + lb[      cg];
                float gf = gsm[ 4096 + c_loc*64 + p_loc] + lb[128 + cg];
                float go = gsm[ 8192 + c_loc*64 + p_loc] + lb[256 + cg];
                float gg = gsm[12288 + c_loc*64 + p_loc] + lb[384 + cg];
                size_t idx = ((size_t)b*128 + cg)*540 + pg;
                float cold = vc[idx] * m;
                float cn = sigm(gf)*cold + sigm(gi)*tanhf(gg);
                float hn = sigm(go)*tanhf(cn);
                vc[idx] = cn;
                if (t == T_-1) vh[idx] = hn;
                hwr[((size_t)b*128 + cg)*640 + (y+1)*22 + x + 1] = f2bf(hn);
                int flat = cg*540 + pg;
                int pos = (flat/2560)*20 + (flat/128)%20;
                int ch  = flat & 127;
                hreA[((size_t)(t*B_ + b)*540 + pos)*128 + ch] = f2bf(hn);
            }
        }
    }
}

// ---------------- core: full T loop in ONE dispatch. one block per b, 1024 threads.
// Reduction-dim splits give every phase >=576 active lanes; 16 waves/CU hide L2 latency.
__global__ __launch_bounds__(1024) void corek3(const unsigned short* __restrict__ hreA,
                                              const float* __restrict__ S,
                                              const unsigned short* __restrict__ pq1, const float* __restrict__ qb1,
                                              const unsigned short* __restrict__ pq2, const float* __restrict__ qb2,
                                              const unsigned short* __restrict__ pq3, const float* __restrict__ qb3,
                                              const unsigned short* __restrict__ pa1, const float* __restrict__ ab1,
                                              const unsigned short* __restrict__ pa2, const float* __restrict__ ab2,
                                              const unsigned short* __restrict__ pih, const unsigned short* __restrict__ phh,
                                              const float* __restrict__ bih, const float* __restrict__ bhh,
                                              const float* __restrict__ reward, const int* __restrict__ lact,
                                              const unsigned char* __restrict__ done,
                                              const float* __restrict__ core_h0, const float* __restrict__ core_c0,
                                              float* __restrict__ ccb, float* __restrict__ outs){
    __shared__ __align__(16) float hs[256];
    __shared__ __align__(16) float cs[256];
    __shared__ __align__(16) float hs2[256];
    __shared__ __align__(16) float q1[128];
    __shared__ __align__(16) float q2[288];
    __shared__ __align__(16) float q3[288];
    __shared__ __align__(16) float elog[4][P_];
    __shared__ __align__(16) float red[48];
    __shared__ __align__(16) float ansv[1056];
    __shared__ __align__(16) float hid[512];
    __shared__ __align__(16) float hidp[512];
    __shared__ __align__(16) float cis[256];
    __shared__ __align__(16) float cisp[3][256];
    __shared__ __align__(16) float gb[1024];
    int b = blockIdx.x, tid = threadIdx.x;
    if (tid < 256){ hs[tid] = core_h0[b*256+tid]; cs[tid] = core_c0[b*256+tid]; }
    if (tid >= 256 && tid < 269) ansv[1043 + (tid-256)] = 0.f;   // pad rows of aw1 -> 0
    __syncthreads();

    for (int t = 0; t < T_; ++t){
        float m = done[t*B_+b] ? 0.f : 1.f;
        // ---- q1 = relu(hs @ qw1 + qb1) : 128 out x 8-way K-split
        {
            int oc = tid >> 3, kc = tid & 7;
            float a0=0.f,a1=0.f,a2=0.f,a3=0.f;
            for (int i4=kc*8; i4<kc*8+8; ++i4){
                ushort4 w = *((const ushort4*)(pq1 + (size_t)((i4<<7)+oc)*4));
                float4 h4 = *((const float4*)(hs + i4*4));
                a0 += h4.x*bfu(w.x); a1 += h4.y*bfu(w.y);
                a2 += h4.z*bfu(w.z); a3 += h4.w*bfu(w.w);
            }
            float a = (a0+a1)+(a2+a3);
            a += __shfl_down(a,4); a += __shfl_down(a,2); a += __shfl_down(a,1);
            if (kc == 0) q1[oc] = fmaxf(qb1[oc] + a, 0.f);
        }
        __syncthreads();
        // ---- q2 = relu(q1 @ qw2 + qb2) : 288 out x 2-way K-split
        if (tid < 576){
            int oc = tid >> 1, kc = tid & 1;
            float a0=0.f,a1=0.f,a2=0.f,a3=0.f;
            for (int i4=kc*16; i4<kc*16+16; ++i4){
                ushort4 w = *((const ushort4*)(pq2 + (size_t)(i4*288+oc)*4));
                float4 h4 = *((const float4*)(q1 + i4*4));
                a0 += h4.x*bfu(w.x); a1 += h4.y*bfu(w.y);
                a2 += h4.z*bfu(w.z); a3 += h4.w*bfu(w.w);
            }
            float a = (a0+a1)+(a2+a3);
            a += __shfl_down(a,1);
            if (kc == 0) q2[oc] = fmaxf(qb2[oc] + a, 0.f);
        }
        __syncthreads();
        // ---- q3 = q2 @ qw3 + qb3 : 288 out x 2-way K-split
        if (tid < 576){
            int oc = tid >> 1, kc = tid & 1;
            float a0=0.f,a1=0.f,a2=0.f,a3=0.f;
            for (int i4=kc*36; i4<kc*36+36; ++i4){
                ushort4 w = *((const ushort4*)(pq3 + (size_t)(i4*288+oc)*4));
                float4 h4 = *((const float4*)(q2 + i4*4));
                a0 += h4.x*bfu(w.x); a1 += h4.y*bfu(w.y);
                a2 += h4.z*bfu(w.z); a3 += h4.w*bfu(w.w);
            }
            float a = (a0+a1)+(a2+a3);
            a += __shfl_down(a,1);
            if (kc == 0){ float v = qb3[oc] + a; q3[oc] = v; ansv[736+oc] = v; }
        }
        if (tid == 0){ float r = reward[t*B_+b]; ansv[1024] = fminf(1.f,fmaxf(-1.f,r)); }
        if (tid >= 32 && tid < 32+NA) ansv[1025 + tid-32] = (lact[t*B_+b] == tid-32) ? 1.f : 0.f;
        __syncthreads();

        // ---- attention logits
        const unsigned short* hrb = hreA + (size_t)(t*B_ + b)*540*128;
        for (int idx = tid; idx < 4*P_; idx += 1024){
            int qi = idx / P_, p = idx % P_;
            const unsigned short* hp = hrb + (size_t)p*128;
            uint4 hv = *((const uint4*)hp);
            const float* qv = q3 + qi*72;
            float a = __uint_as_float(hv.x<<16)*qv[0] + __uint_as_float(hv.x & 0xffff0000u)*qv[1]
                    + __uint_as_float(hv.y<<16)*qv[2] + __uint_as_float(hv.y & 0xffff0000u)*qv[3]
                    + __uint_as_float(hv.z<<16)*qv[4] + __uint_as_float(hv.z & 0xffff0000u)*qv[5]
                    + __uint_as_float(hv.w<<16)*qv[6] + __uint_as_float(hv.w & 0xffff0000u)*qv[7];
            const float* Sp = S + p*64;
            #pragma unroll
            for (int s2=0;s2<16;++s2){
                float4 sv = *((const float4*)(Sp + 4*s2));
                a += sv.x*qv[8+4*s2] + sv.y*qv[9+4*s2] + sv.z*qv[10+4*s2] + sv.w*qv[11+4*s2];
            }
            elog[qi][p] = a;
        }
        __syncthreads();
        // ---- softmax per query: 256 lanes each
        {
            int qi = tid >> 8, lt = tid & 255;
            float mx = -1e30f;
            for (int p = lt; p < P_; p += 256) mx = fmaxf(mx, elog[qi][p]);
            for (int off=32; off; off>>=1) mx = fmaxf(mx, __shfl_down(mx, off));
            if ((tid & 63) == 0) red[tid>>6] = mx;
            __syncthreads();
            if (tid < 4) red[16+tid] = fmaxf(fmaxf(red[tid*4],red[tid*4+1]), fmaxf(red[tid*4+2],red[tid*4+3]));
            __syncthreads();
            mx = red[16+qi];
            float sm = 0.f;
            for (int p = lt; p < P_; p += 256){ float e = expf(elog[qi][p]-mx); elog[qi][p] = e; sm += e; }
            for (int off=32; off; off>>=1) sm += __shfl_down(sm, off);
            if ((tid & 63) == 0) red[24 + (tid>>6)] = sm;
            __syncthreads();
            if (tid < 4) red[40+tid] = red[24+tid*4]+red[24+tid*4+1]+red[24+tid*4+2]+red[24+tid*4+3];
            __syncthreads();
        }
        // ---- ans = softmax(A) @ V : 8-lane p-split + shfl reduce
        if (tid < 480){
            int g = tid >> 3;            // 60 groups: qi x vb(15 x 8ch)
            int qi = g / 15, vb = g % 15;
            int pc = tid & 7;
            float ac[8] = {0,0,0,0,0,0,0,0};
            const unsigned short* hb8 = hrb + 8 + vb*8;
            for (int p = pc; p < P_; p += 8){
                float e = elog[qi][p];
                uint4 hv = *((const uint4*)(hb8 + (size_t)p*128));
                ac[0] += e*__uint_as_float(hv.x<<16);
                ac[1] += e*__uint_as_float(hv.x & 0xffff0000u);
                ac[2] += e*__uint_as_float(hv.y<<16);
                ac[3] += e*__uint_as_float(hv.y & 0xffff0000u);
                ac[4] += e*__uint_as_float(hv.z<<16);
                ac[5] += e*__uint_as_float(hv.z & 0xffff0000u);
                ac[6] += e*__uint_as_float(hv.w<<16);
                ac[7] += e*__uint_as_float(hv.w & 0xffff0000u);
            }
            #pragma unroll
            for (int j=0;j<8;++j){ ac[j] += __shfl_down(ac[j],4); ac[j] += __shfl_down(ac[j],2); ac[j] += __shfl_down(ac[j],1); }
            if (pc == 0){
                float inv2 = 1.f/red[40+qi];
                #pragma unroll
                for (int j=0;j<8;++j) ansv[qi*184 + vb*8 + j] = ac[j]*inv2;
            }
        } else if (tid < 992){
            int u = tid - 480;
            int g = u >> 3;              // 64 groups: qi x vb4(16 x 4 floats of S)
            int qi = g >> 4, vb4 = g & 15;
            int pc = u & 7;
            float ac[4] = {0,0,0,0};
            const float* Sp = S + vb4*4;
            for (int p = pc; p < P_; p += 8){
                float e = elog[qi][p];
                float4 sv = *((const float4*)(Sp + (size_t)p*64));
                ac[0]+=e*sv.x; ac[1]+=e*sv.y; ac[2]+=e*sv.z; ac[3]+=e*sv.w;
            }
            #pragma unroll
            for (int j=0;j<4;++j){ ac[j] += __shfl_down(ac[j],4); ac[j] += __shfl_down(ac[j],2); ac[j] += __shfl_down(ac[j],1); }
            if (pc == 0){
                float inv2 = 1.f/red[40+qi];
                #pragma unroll
                for (int j=0;j<4;++j) ansv[qi*184 + 120 + vb4*4 + j] = ac[j]*inv2;
            }
        }
        __syncthreads();
        // ---- hid = relu(ansv @ aw1 + ab1) : 512 out x 2-way K-split
        float aw1a;
        {
            int oc = tid & 511, kc = tid >> 9;
            int i0 = kc ? 131 : 0, i1 = kc ? 261 : 131;
            float a0=0.f,a1=0.f,a2=0.f,a3=0.f;
            for (int i4=i0;i4<i1;++i4){
                ushort4 w = *((const ushort4*)(pa1 + (size_t)((i4<<9)+oc)*4));
                float4 av = *((const float4*)(ansv + i4*4));
                a0 += av.x*bfu(w.x); a1 += av.y*bfu(w.y);
                a2 += av.z*bfu(w.z); a3 += av.w*bfu(w.w);
            }
            aw1a = (a0+a1)+(a2+a3);
            if (kc) hidp[oc] = aw1a;
        }
        __syncthreads();
        if (tid < 512) hid[tid] = fmaxf(ab1[tid] + aw1a + hidp[tid], 0.f);
        else { int t2 = tid - 512; if (t2 < 256) hs2[t2] = hs[t2]*m; }
        __syncthreads();
        // ---- cis = hid @ aw2 + ab2 : 256 out x 4-way K-split
        float aw2a;
        {
            int oc = tid & 255, kc = tid >> 8;
            float a0=0.f,a1=0.f,a2=0.f,a3=0.f;
            for (int i4=kc*32; i4<kc*32+32; ++i4){
                ushort4 w = *((const ushort4*)(pa2 + (size_t)((i4<<8)+oc)*4));
                float4 hv = *((const float4*)(hid + i4*4));
                a0 += hv.x*bfu(w.x); a1 += hv.y*bfu(w.y);
                a2 += hv.z*bfu(w.z); a3 += hv.w*bfu(w.w);
            }
            aw2a = (a0+a1)+(a2+a3);
            if (kc) cisp[kc-1][oc] = aw2a;
        }
        __syncthreads();
        if (tid < 256) cis[tid] = ab2[tid] + aw2a + cisp[0][tid] + cisp[1][tid] + cisp[2][tid];
        __syncthreads();
        // ---- gates = cis @ w_ih^T + hs2 @ w_hh^T + b : 1024 out x 1
        {
            int g = tid;
            float a0=bih[g]+bhh[g], a1=0.f, a2=0.f, a3=0.f;
            for (int i4=0;i4<64;++i4){
                ushort4 wi = *((const ushort4*)(pih + (size_t)((i4<<10)+g)*4));
                ushort4 wh = *((const ushort4*)(phh + (size_t)((i4<<10)+g)*4));
                float4 cv = *((const float4*)(cis + i4*4));
                float4 hv = *((const float4*)(hs2 + i4*4));
                a0 += cv.x*bfu(wi.x) + hv.x*bfu(wh.x);
                a1 += cv.y*bfu(wi.y) + hv.y*bfu(wh.y);
                a2 += cv.z*bfu(wi.z) + hv.z*bfu(wh.z);
                a3 += cv.w*bfu(wi.w) + hv.w*bfu(wh.w);
            }
            gb[g] = (a0+a1)+(a2+a3);
        }
        __syncthreads();
        if (tid < 256){
            float gi = gb[tid], gf = gb[256+tid], gg = gb[512+tid], go = gb[768+tid];
            float cold = cs[tid]*m;
            float cn = sigm(gf)*cold + sigm(gi)*tanhf(gg);
            float hn = sigm(go)*tanhf(cn);
            cs[tid] = cn;
            hs[tid] = hn;
            outs[(t*B_+b)*256+tid] = hn;
        }
        __syncthreads();
    }
    if (tid < 256) ccb[b*256+tid] = cs[tid];
}

// ---------------- heads
__global__ __launch_bounds__(64) void finalk(const float* __restrict__ outs,
                                             const float* __restrict__ pw, const float* __restrict__ pb,
                                             const float* __restrict__ vw, const float* __restrict__ vb,
                                             float* __restrict__ dout){
    int row = blockIdx.x, tid = threadIdx.x;
    __shared__ float os[256];
    __shared__ float lg[NA];
    for (int i=tid; i<256; i+=64) os[i] = outs[row*256+i];
    __syncthreads();
    if (tid < NA){
        float a = pb[tid];
        for (int i=0;i<256;++i) a += os[i]*pw[i*NA+tid];
        lg[tid] = a;
        dout[row*NA + tid] = a;
    } else if (tid == 32){
        float a = vb[0];
        for (int i=0;i<256;++i) a += os[i]*vw[i];
        dout[9216 + row] = a;
    }
    __syncthreads();
    if (tid == 0){
        int am = 0; float bv = lg[0];
        for (int j=1;j<NA;++j) if (lg[j] > bv){ bv = lg[j]; am = j; }
        dout[9728 + row] = (float)am;
    }
}

extern "C" void kernel_launch(void* const* d_in, const int* in_sizes, int n_in,
                              void* d_out, int out_size, void* d_ws, size_t ws_size,
                              hipStream_t stream) {
    const float* frame   = (const float*)d_in[0];
    const unsigned char* done = (const unsigned char*)d_in[1];
    const int*   lact    = (const int*)d_in[2];
    const float* reward  = (const float*)d_in[3];
    const float* core_h0 = (const float*)d_in[4];
    const float* core_c0 = (const float*)d_in[5];
    const float* conv_h0 = (const float*)d_in[6];
    const float* conv_c0 = (const float*)d_in[7];
    const float* cnn_w1  = (const float*)d_in[8];
    const float* cnn_b1  = (const float*)d_in[9];
    const float* cnn_w2  = (const float*)d_in[10];
    const float* cnn_b2  = (const float*)d_in[11];
    const float* lstm_w  = (const float*)d_in[12];
    const float* lstm_b  = (const float*)d_in[13];
    const float* qw1 = (const float*)d_in[14]; const float* qb1 = (const float*)d_in[15];
    const float* qw2 = (const float*)d_in[16]; const float* qb2 = (const float*)d_in[17];
    const float* qw3 = (const float*)d_in[18]; const float* qb3 = (const float*)d_in[19];
    const float* aw1 = (const float*)d_in[20]; const float* ab1 = (const float*)d_in[21];
    const float* aw2 = (const float*)d_in[22]; const float* ab2 = (const float*)d_in[23];
    const float* w_ih = (const float*)d_in[24]; const float* w_hh = (const float*)d_in[25];
    const float* b_ih = (const float*)d_in[26]; const float* b_hh = (const float*)d_in[27];
    const float* pw = (const float*)d_in[28]; const float* pb = (const float*)d_in[29];
    const float* vw = (const float*)d_in[30]; const float* vb = (const float*)d_in[31];

    float* ws = (float*)d_ws;
    float* dout = (float*)d_out;

    // ws layout (float offsets). c1pad is transient: consumed by c2mfma, then
    // hreA/apack/weight-packs are written into that range (after c2mfma in stream order).
    unsigned short* xpad   = (unsigned short*)ws;                         // 20,971,520 u16
    unsigned short* c1pad  = (unsigned short*)(ws + 10485760);            // 38,535,168 u16 (transient)
    unsigned short* hreA   = (unsigned short*)(ws + 10485760);            // 35,389,440 u16
    unsigned short* apack  = (unsigned short*)(ws + 28180480);            // 1,572,864 u16
    unsigned short* wpk    = (unsigned short*)(ws + 28966912);            // packed core weights (bf16)
    unsigned short* pq1 = wpk;            // 32768
    unsigned short* pq2 = wpk + 32768;    // 36864
    unsigned short* pq3 = wpk + 69632;    // 82944
    unsigned short* pa1 = wpk + 152576;   // 534528
    unsigned short* pa2 = wpk + 687104;   // 131072
    unsigned short* pih = wpk + 818176;   // 262144
    unsigned short* phh = wpk + 1080320;  // ends 1,342,464
    unsigned short* hpad0  = (unsigned short*)(ws + 29753344);            // 1,310,720 u16
    unsigned short* apack2 = (unsigned short*)(ws + 30408704);            // 32,768 u16
    unsigned short* hpad1  = (unsigned short*)(ws + 30425088);            // 1,310,720 u16 (old gates region)
    float* vh    = ws + 34881536;      // 1,105,920
    float* vc    = ws + 35987456;      // 1,105,920
    float* S     = ws + 37093376;      // 34,560
    float* outs  = ws + 37127936;      // 131,072
    float* ccb   = ws + 37259008;      // 4,096    (total 37,263,104 floats = 149 MB)

    // zero padded planes (interiors overwritten)
    hipMemsetAsync(xpad,  0, (size_t)20971520*2, stream);
    hipMemsetAsync(c1pad, 0, (size_t)38535168*2, stream);

    // CNN
    apack2k<<<128, 256, 0, stream>>>(cnn_w2, apack2);
    conv1k<<<512*52, 256, 0, stream>>>(frame, cnn_w1, cnn_b1, c1pad);
    c2mfma<<<2560, 256, 0, stream>>>(c1pad, apack2, cnn_b2, xpad);

    // c1pad is dead from here on — its range is reused below
    hipMemsetAsync(hpad0, 0, (size_t)1310720*2, stream);
    hipMemsetAsync(hpad1, 0, (size_t)1310720*2, stream);
    sbasisk<<<135, 256, 0, stream>>>(S);
    apackk<<<6144, 256, 0, stream>>>(lstm_w, apack);
    // core-weight bf16 x4 packs (2.68 MB total -> L2-resident in corek3)
    packw4k<<<128,  256, 0, stream>>>(qw1, pq1, 256, 128);
    packw4k<<<144,  256, 0, stream>>>(qw2, pq2, 128, 288);
    packw4k<<<324,  256, 0, stream>>>(qw3, pq3, 288, 288);
    packw4k<<<2088, 256, 0, stream>>>(aw1, pa1, 1043, 512);
    packw4k<<<512,  256, 0, stream>>>(aw2, pa2, 512, 256);
    packt4k<<<1024, 256, 0, stream>>>(w_ih, pih, 256, 1024);
    packt4k<<<1024, 256, 0, stream>>>(w_hh, phh, 256, 1024);
    h0packk<<<4320, 256, 0, stream>>>(conv_h0, hpad0);
    hipMemcpyAsync(vc,  conv_c0, (size_t)16*128*540*sizeof(float), hipMemcpyDeviceToDevice, stream);

    // phase A: vis ConvLSTM over all t, fully fused (GEMM + pointwise per dispatch)
    for (int t = 0; t < T_; ++t){
        gvk<<<288, 256, 0, stream>>>(xpad, (t&1)?hpad1:hpad0, (t&1)?hpad0:hpad1,
                                     apack, lstm_b, done, vh, vc, hreA, t);
    }

    // phase B: entire core recurrence in one dispatch
    corek3<<<16, 1024, 0, stream>>>(hreA, S, pq1,qb1,pq2,qb2,pq3,qb3,
                                   pa1,ab1,pa2,ab2, pih,phh,b_ih,b_hh,
                                   reward, lact, done, core_h0, core_c0, ccb, outs);

    finalk<<<512, 64, 0, stream>>>(outs, pw, pb, vw, vb, dout);

    hipMemcpyAsync(dout + 10240,   outs + (size_t)31*B_*256, (size_t)16*256*sizeof(float), hipMemcpyDeviceToDevice, stream);
    hipMemcpyAsync(dout + 14336,   ccb, (size_t)16*256*sizeof(float), hipMemcpyDeviceToDevice, stream);
    hipMemcpyAsync(dout + 18432,   vh,  (size_t)16*128*540*sizeof(float), hipMemcpyDeviceToDevice, stream);
    hipMemcpyAsync(dout + 1124352, vc,  (size_t)16*128*540*sizeof(float), hipMemcpyDeviceToDevice, stream);
}

// Round 3
// 5548.684 us; speedup vs baseline: 1.8277x; 1.8277x over previous
//
#include <hip/hip_runtime.h>
#include <math.h>

#define T_ 32
#define B_ 16
#define NA 18
#define P_ 540   // 27*20

typedef __attribute__((ext_vector_type(8)))  short short8;
typedef __attribute__((ext_vector_type(16))) float f32x16;

__device__ __forceinline__ float sigm(float x){ return 1.0f/(1.0f+expf(-x)); }
__device__ __forceinline__ unsigned short f2bf(float f){
    unsigned u = __float_as_uint(f);
    u += 0x7fff + ((u>>16)&1u);
    return (unsigned short)(u>>16);
}
__device__ __forceinline__ float bfu(unsigned short u){ return __uint_as_float(((unsigned)u)<<16); }

// ---------------- conv1: (512,3,210,160) -> c1pad bf16 [512][32][56][42], k8 s4 padH(1,1) W(2,2)
__global__ __launch_bounds__(256) void conv1k(const float* __restrict__ frame,
                                              const float* __restrict__ w,
                                              const float* __restrict__ bias,
                                              unsigned short* __restrict__ c1pad){
    __shared__ float tile[4032];  // 3ch * 8rows * 168cols (padded)
    int bid = blockIdx.x;
    int n = bid / 52, oh = bid % 52;
    int tid = threadIdx.x;
    const float* fb = frame + (size_t)n*3*210*160;
    for (int s = tid; s < 4032; s += 256){
        int col = s % 168;
        int row = (s/168) & 7;
        int ic  = s / 1344;
        int iy = oh*4 - 1 + row;
        int ix = col - 2;
        float v = 0.f;
        if (iy >= 0 && iy < 210 && ix >= 0 && ix < 160) v = fb[ic*33600 + iy*160 + ix];
        tile[s] = v;
    }
    __syncthreads();
    int oc = tid & 31, grp = tid >> 5;      // grp 0..7 -> ow = grp*5..grp*5+4
    float acc[5] = {0.f,0.f,0.f,0.f,0.f};
    const float* wb = w + oc*192;
    for (int ic=0; ic<3; ++ic){
        #pragma unroll
        for (int kh=0; kh<8; ++kh){
            const float* wr = wb + ic*64 + kh*8;
            float4 w0 = *((const float4*)wr);
            float4 w1 = *((const float4*)(wr+4));
            const float* row = tile + ic*1344 + kh*168 + grp*20;
            float r[24];
            *((float4*)(r+ 0)) = *((const float4*)(row+ 0));
            *((float4*)(r+ 4)) = *((const float4*)(row+ 4));
            *((float4*)(r+ 8)) = *((const float4*)(row+ 8));
            *((float4*)(r+12)) = *((const float4*)(row+12));
            *((float4*)(r+16)) = *((const float4*)(row+16));
            *((float4*)(r+20)) = *((const float4*)(row+20));
            #pragma unroll
            for (int o=0;o<5;++o){
                acc[o] += r[o*4+0]*w0.x + r[o*4+1]*w0.y + r[o*4+2]*w0.z + r[o*4+3]*w0.w
                        + r[o*4+4]*w1.x + r[o*4+5]*w1.y + r[o*4+6]*w1.z + r[o*4+7]*w1.w;
            }
        }
    }
    float bi = bias[oc];
    unsigned short* ob = c1pad + ((size_t)(n*32 + oc)*56 + oh+2)*42 + 1;
    #pragma unroll
    for (int o=0;o<5;++o) ob[grp*5+o] = f2bf(acc[o] + bi);
}

// ---------------- conv2 A-pack: cnn_w2 (64,32,4,4) -> apack2[32 ic][2 mt][64 lane][8] bf16
__global__ void apack2k(const float* __restrict__ w2, unsigned short* __restrict__ ap){
    int idx = blockIdx.x*256 + threadIdx.x;
    if (idx >= 32768) return;
    int j = idx & 7;
    int lane = (idx>>3) & 63;
    int mt = (idx>>9) & 1;
    int ic = idx >> 10;
    int k = ((lane>>5)<<3) + j;          // kh*4+kw
    int oc = mt*32 + (lane & 31);
    ap[idx] = f2bf(w2[((oc*32 + ic)<<4) + k]);
}

// ---------------- conv2 MFMA: c1pad bf16 -> xpad bf16 [512][64][640], k4 s2 padH(2,2) W(1,1)
__global__ __launch_bounds__(256) void c2mfma(const unsigned short* __restrict__ c1pad,
                                              const unsigned short* __restrict__ apack2,
                                              const float* __restrict__ bias,
                                              unsigned short* __restrict__ xpad){
    __shared__ unsigned short p2[2][3072];   // [n 128][stride 24]
    __shared__ float bsm[64];
    int bid = blockIdx.x;
    int s = bid / 5;
    int n0 = (bid % 5) * 128;
    int tid = threadIdx.x;
    int wave = tid >> 6, lane = tid & 63;
    int khalf = (lane>>5) << 3;
    if (tid < 64) bsm[tid] = bias[tid];
    const unsigned short* cb = c1pad + (size_t)s*32*2352;

    int soff[8], swaddr[8];
    #pragma unroll
    for (int q=0;q<8;++q){
        int idx = q*256 + tid;
        int n = idx & 127, k = idx >> 7;
        int p = n0 + n; if (p > 539) p = 539;
        soff[q] = ((p/20)*2 + (k>>2))*42 + (p%20)*2 + (k&3);
        swaddr[q] = n*24 + k;
    }
    #pragma unroll
    for (int q=0;q<8;++q) p2[0][swaddr[q]] = cb[soff[q]];
    unsigned short rv[8];
    #pragma unroll
    for (int q=0;q<8;++q) rv[q] = cb[2352 + soff[q]];

    int mt = wave >> 1, ntb = (wave & 1) * 2;
    short8 acur = *((const short8*)(apack2 + ((size_t)mt*64 + lane)*8));
    short8 anxt;
    f32x16 acc[2];
    #pragma unroll
    for (int jj=0;jj<2;++jj)
        #pragma unroll
        for (int rg=0;rg<16;++rg) acc[jj][rg] = 0.f;
    __syncthreads();

    for (int c=0; c<32; ++c){
        int buf = c & 1;
        if (c < 31){
            #pragma unroll
            for (int q=0;q<8;++q) p2[buf^1][swaddr[q]] = rv[q];
        }
        if (c < 30){
            const unsigned short* src = cb + (size_t)(c+2)*2352;
            #pragma unroll
            for (int q=0;q<8;++q) rv[q] = src[soff[q]];
        }
        if (c < 31) anxt = *((const short8*)(apack2 + ((size_t)((c+1)*2 + mt)*64 + lane)*8));
        #pragma unroll
        for (int jj=0;jj<2;++jj){
            int n = (ntb+jj)*32 + (lane & 31);
            short8 bf = *((const short8*)(&p2[buf][n*24 + khalf]));
            acc[jj] = __builtin_amdgcn_mfma_f32_32x32x16_bf16(acur, bf, acc[jj], 0, 0, 0);
        }
        acur = anxt;
        __syncthreads();
    }
    #pragma unroll
    for (int jj=0;jj<2;++jj){
        int pos = n0 + (ntb+jj)*32 + (lane & 31);
        if (pos >= 540) continue;
        int y = pos/20, x = pos%20;
        unsigned short* op = xpad + (size_t)s*64*640 + (y+1)*22 + x + 1;
        #pragma unroll
        for (int rg=0; rg<16; ++rg){
            int oc = mt*32 + (rg & 3) + 8*(rg>>2) + 4*(lane>>5);
            op[(size_t)oc*640] = f2bf(acc[jj][rg] + bsm[oc]);
        }
    }
}

// ---------------- spatial basis S[540][64]
__global__ void sbasisk(float* __restrict__ S){
    int idx = blockIdx.x*256 + threadIdx.x;
    if (idx >= P_*64) return;
    int s = idx & 63, p = idx >> 6;
    int y = p/20, x = p%20;
    int u = s >> 3, v = s & 7;
    double a  = cos((double)((y+1)*(u+1)) * M_PI / 27.0);
    double bb = cos((double)((x+1)*(v+1)) * M_PI / 20.0);
    S[idx] = (float)(a*bb);
}

// ---------------- weight pack: f32 [R][C] -> bf16 [(R+3)/4][C][4]  (pad rows -> 0)
__global__ void packw4k(const float* __restrict__ in, unsigned short* __restrict__ out, int R, int C){
    int idx = blockIdx.x*256 + threadIdx.x;
    int r4cnt = (R+3)>>2;
    if (idx >= r4cnt*C*4) return;
    int j = idx & 3;
    int rc = idx >> 2;
    int c = rc % C;
    int r = (rc / C)*4 + j;
    out[idx] = (r < R) ? f2bf(in[(size_t)r*C + c]) : (unsigned short)0;
}
// ---------------- weight pack (transposed input): f32 [C][R] -> bf16 [(R+3)/4][C][4]
__global__ void packt4k(const float* __restrict__ in, unsigned short* __restrict__ out, int R, int C){
    int idx = blockIdx.x*256 + threadIdx.x;
    int r4cnt = (R+3)>>2;
    if (idx >= r4cnt*C*4) return;
    int j = idx & 3;
    int rc = idx >> 2;
    int c = rc % C;
    int r = (rc / C)*4 + j;
    out[idx] = (r < R) ? f2bf(in[(size_t)c*R + r]) : (unsigned short)0;
}

// ---------------- gates A-pack: lstm_w (512,192,3,3) -> apack[192][16][64][8] bf16 (k>=9 -> 0)
__global__ void apackk(const float* __restrict__ lw, unsigned short* __restrict__ ap){
    int idx = blockIdx.x*256 + threadIdx.x;
    if (idx >= 1572864) return;
    int j = idx & 7;
    int lane = (idx>>3) & 63;
    int mt = (idx>>9) & 15;
    int ch = idx >> 13;
    int kk = ((lane>>5)<<3) + j;
    int oc = mt*32 + (lane & 31);
    ap[idx] = (kk < 9) ? f2bf(lw[(size_t)oc*1728 + ch*9 + kk]) : (unsigned short)0;
}

// ---------------- pack conv_h0 fp32 -> hpad bf16 interior
__global__ void h0packk(const float* __restrict__ h0, unsigned short* __restrict__ hpad){
    int idx = blockIdx.x*256 + threadIdx.x;
    if (idx >= 16*128*540) return;
    int plane = idx / 540, p = idx % 540;
    hpad[(size_t)plane*640 + (p/20+1)*22 + (p%20) + 1] = f2bf(h0[idx]);
}

// =====================================================================================
// gvck: ONE dispatch per t does BOTH pipeline stages concurrently:
//   blocks 0..287  : vis ConvLSTM step t (gates MFMA + fused pointwise), 8 waves
//   blocks 288..303: core recurrence step t-1 (reads hreA[t-1] written by PREVIOUS
//                    dispatch -> stream-ordered, race-free). hs/cs persist in ws.
// Loop runs t = 0..T_ (33 dispatches); t==0 has no core work, t==T_ no vis work.
// =====================================================================================
__global__ __launch_bounds__(512) void gvck(const unsigned short* __restrict__ xpad,
                                            const unsigned short* __restrict__ hrd,
                                            unsigned short* __restrict__ hwr,
                                            const unsigned short* __restrict__ apack,
                                            const float* __restrict__ lb,
                                            const unsigned char* __restrict__ done,
                                            float* __restrict__ vh, float* __restrict__ vc,
                                            unsigned short* __restrict__ hreA,
                                            const float* __restrict__ S,
                                            const unsigned short* __restrict__ pq1, const float* __restrict__ qb1,
                                            const unsigned short* __restrict__ pq2, const float* __restrict__ qb2,
                                            const unsigned short* __restrict__ pq3, const float* __restrict__ qb3,
                                            const unsigned short* __restrict__ pa1, const float* __restrict__ ab1,
                                            const unsigned short* __restrict__ pa2, const float* __restrict__ ab2,
                                            const unsigned short* __restrict__ pih, const unsigned short* __restrict__ phh,
                                            const float* __restrict__ bih, const float* __restrict__ bhh,
                                            const float* __restrict__ reward, const int* __restrict__ lact,
                                            float* __restrict__ hsb, float* __restrict__ csb,
                                            float* __restrict__ outs,
                                            int t){
    __shared__ __align__(16) unsigned char smraw[65536];
    int bid = blockIdx.x;
    int tid = threadIdx.x;

    if (bid < 288){
        // ---------------- vis ConvLSTM step t ----------------
        if (t >= T_) return;
        unsigned short (*panel)[6144] = (unsigned short (*)[6144])smraw;  // 24.5 KB during K-loop
        float* gsm = (float*)smraw;                                       // 64 KB after K-loop
        int b  = bid % 16;
        int r  = bid / 16;
        int nb = r % 9;
        int mh = r / 9;
        int wave = tid >> 6, lane = tid & 63;
        int khalf = (lane>>5) << 3;
        int n0 = nb * 64;
        bool dn = done[t*B_ + b];

        const unsigned short* xb = xpad + ((size_t)(t*B_ + b))*64*640;
        const unsigned short* hb = hrd + (size_t)b*128*640;

        int soff[5], swaddr[5], gq[5];
        bool act[5];
        #pragma unroll
        for (int q=0;q<5;++q){
            int idx = q*512 + tid;
            act[q] = idx < 2304;
            int idc = act[q] ? idx : 0;
            int g = idc / 576;
            int rr = idc % 576;
            int k = rr / 64, n = rr & 63;
            int p = n0 + n; if (p > 539) p = 539;
            int pbase = (p/20)*22 + (p%20);
            soff[q] = pbase + (k/3)*22 + (k%3);
            swaddr[q] = g*1536 + n*24 + k;
            gq[q] = g;
        }
        // zero padding k-rows 9..15 of both buffers
        for (int s2 = tid; s2 < 3584; s2 += 512){
            int bf2 = s2 / 1792, r2 = s2 % 1792;
            int g2 = r2 / 448, rr2 = r2 % 448;
            panel[bf2][g2*1536 + (rr2 & 63)*24 + 9 + (rr2>>6)] = 0;
        }
        #pragma unroll
        for (int q=0;q<5;++q) if (act[q]) panel[0][swaddr[q]] = xb[gq[q]*640 + soff[q]];
        unsigned short rv[5];
        #pragma unroll
        for (int q=0;q<5;++q) rv[q] = act[q] ? xb[(4+gq[q])*640 + soff[q]] : (unsigned short)0;

        // wave -> (gate, half): mt = gate*4 + mh*2 + half
        int mt = (wave>>1)*4 + mh*2 + (wave&1);
        short8 acur[4], anxt[4];
        #pragma unroll
        for (int kc=0;kc<4;++kc)
            acur[kc] = *((const short8*)(apack + ((size_t)(kc*16 + mt)*64 + lane)*8));

        f32x16 acc[2];
        #pragma unroll
        for (int j=0;j<2;++j)
            #pragma unroll
            for (int rg=0;rg<16;++rg) acc[j][rg] = 0.f;
        __syncthreads();

        for (int it=0; it<48; ++it){
            int buf = it & 1;
            if (it < 47){
                #pragma unroll
                for (int q=0;q<5;++q) if (act[q]) panel[buf^1][swaddr[q]] = rv[q];
            }
            if (it < 46){
                int icb = (it+2)*4;
                #pragma unroll
                for (int q=0;q<5;++q){
                    if (act[q]){
                        int ic = icb + gq[q];
                        rv[q] = (ic < 64) ? xb[ic*640 + soff[q]]
                                          : (dn ? (unsigned short)0 : hb[(ic-64)*640 + soff[q]]);
                    }
                }
            }
            if (it < 47){
                int cb2 = (it+1)*4;
                #pragma unroll
                for (int kc=0;kc<4;++kc)
                    anxt[kc] = *((const short8*)(apack + ((size_t)((cb2+kc)*16 + mt)*64 + lane)*8));
            }
            #pragma unroll
            for (int kc=0;kc<4;++kc){
                #pragma unroll
                for (int j=0;j<2;++j){
                    int n = j*32 + (lane & 31);
                    short8 bf = *((const short8*)(&panel[buf][kc*1536 + n*24 + khalf]));
                    acc[j] = __builtin_amdgcn_mfma_f32_32x32x16_bf16(acur[kc], bf, acc[j], 0, 0, 0);
                }
            }
            #pragma unroll
            for (int kc=0;kc<4;++kc) acur[kc] = anxt[kc];
            __syncthreads();
        }

        // stage gates to LDS: gsm[gate][c_loc][p_loc]
        int g8 = wave >> 1, ih = wave & 1;
        #pragma unroll
        for (int j=0;j<2;++j){
            int p_loc = j*32 + (lane & 31);
            #pragma unroll
            for (int rg=0; rg<16; ++rg){
                int c_loc = ih*32 + 4*(lane>>5) + (rg & 3) + 8*(rg>>2);
                gsm[g8*4096 + c_loc*64 + p_loc] = acc[j][rg];
            }
        }
        __syncthreads();

        // fused LSTM pointwise: 512 threads x 8 elements over 64c x 64p
        {
            int p_loc = tid & 63, c0 = tid >> 6;
            int pg = n0 + p_loc;
            if (pg < 540){
                float m = dn ? 0.f : 1.f;
                int y = pg/20, x = pg%20;
                #pragma unroll
                for (int e=0;e<8;++e){
                    int c_loc = c0*8 + e;
                    int cg = mh*64 + c_loc;
                    float gi = gsm[        c_loc*64 + p_loc] + lb[      cg];
                    float gf = gsm[ 4096 + c_loc*64 + p_loc] + lb[128 + cg];
                    float go = gsm[ 8192 + c_loc*64 + p_loc] + lb[256 + cg];
                    float gg = gsm[12288 + c_loc*64 + p_loc] + lb[384 + cg];
                    size_t idx = ((size_t)b*128 + cg)*540 + pg;
                    float cold = vc[idx] * m;
                    float cn = sigm(gf)*cold + sigm(gi)*tanhf(gg);
                    float hn = sigm(go)*tanhf(cn);
                    vc[idx] = cn;
                    if (t == T_-1) vh[idx] = hn;
                    hwr[((size_t)b*128 + cg)*640 + (y+1)*22 + x + 1] = f2bf(hn);
                    int flat = cg*540 + pg;
                    int pos = (flat/2560)*20 + (flat/128)%20;
                    int ch  = flat & 127;
                    hreA[((size_t)(t*B_ + b)*540 + pos)*128 + ch] = f2bf(hn);
                }
            }
        }
        return;
    }

    // ---------------- core recurrence step tc = t-1 ----------------
    if (t == 0) return;
    int tc = t - 1;
    int b = bid - 288;
    float* fs = (float*)smraw;
    float* hs   = fs;          // 256
    float* cs   = fs + 256;    // 256
    float* hs2  = fs + 512;    // 256
    float* q1   = fs + 768;    // 128
    float* q2   = fs + 896;    // 288
    float* q3   = fs + 1184;   // 288
    float* elog = fs + 1472;   // 4*540
    float* red  = fs + 3632;   // 32
    float* ansv = fs + 3664;   // 1056
    float* hid  = fs + 4720;   // 512
    float* cis  = fs + 5232;   // 256
    float* gb   = fs + 5488;   // 1024  (ends 6512 floats = 26 KB)

    if (tid < 256){ hs[tid] = hsb[b*256+tid]; cs[tid] = csb[b*256+tid]; }
    if (tid >= 256 && tid < 269) ansv[1043 + (tid-256)] = 0.f;   // pad rows of aw1 -> 0
    __syncthreads();

    float m = done[tc*B_+b] ? 0.f : 1.f;
    // ---- q1 = relu(hs @ qw1 + qb1)
    if (tid < 128){
        float a0=0.f,a1=0.f,a2=0.f,a3=0.f;
        for (int i4=0;i4<64;++i4){
            ushort4 w = *((const ushort4*)(pq1 + (size_t)((i4<<7)+tid)*4));
            float4 h4 = *((const float4*)(hs + i4*4));
            a0 += h4.x*bfu(w.x); a1 += h4.y*bfu(w.y);
            a2 += h4.z*bfu(w.z); a3 += h4.w*bfu(w.w);
        }
        q1[tid] = fmaxf(qb1[tid] + ((a0+a1)+(a2+a3)), 0.f);
    }
    __syncthreads();
    // ---- q2 = relu(q1 @ qw2 + qb2)
    if (tid < 288){
        float a0=0.f,a1=0.f,a2=0.f,a3=0.f;
        for (int i4=0;i4<32;++i4){
            ushort4 w = *((const ushort4*)(pq2 + (size_t)(i4*288+tid)*4));
            float4 h4 = *((const float4*)(q1 + i4*4));
            a0 += h4.x*bfu(w.x); a1 += h4.y*bfu(w.y);
            a2 += h4.z*bfu(w.z); a3 += h4.w*bfu(w.w);
        }
        q2[tid] = fmaxf(qb2[tid] + ((a0+a1)+(a2+a3)), 0.f);
    }
    __syncthreads();
    // ---- q3 = q2 @ qw3 + qb3
    if (tid < 288){
        float a0=0.f,a1=0.f,a2=0.f,a3=0.f;
        for (int i4=0;i4<72;++i4){
            ushort4 w = *((const ushort4*)(pq3 + (size_t)(i4*288+tid)*4));
            float4 h4 = *((const float4*)(q2 + i4*4));
            a0 += h4.x*bfu(w.x); a1 += h4.y*bfu(w.y);
            a2 += h4.z*bfu(w.z); a3 += h4.w*bfu(w.w);
        }
        float a = qb3[tid] + ((a0+a1)+(a2+a3));
        q3[tid] = a;
        ansv[736+tid] = a;
    }
    if (tid == 0){ float r = reward[tc*B_+b]; ansv[1024] = fminf(1.f,fmaxf(-1.f,r)); }
    if (tid >= 32 && tid < 32+NA) ansv[1025 + tid-32] = (lact[tc*B_+b] == tid-32) ? 1.f : 0.f;
    __syncthreads();

    // ---- attention logits
    const unsigned short* hrb = hreA + (size_t)(tc*B_ + b)*540*128;
    for (int idx = tid; idx < 4*P_; idx += 512){
        int qi = idx / P_, p = idx % P_;
        const unsigned short* hp = hrb + (size_t)p*128;
        uint4 hv = *((const uint4*)hp);
        const float* qv = q3 + qi*72;
        float a = __uint_as_float(hv.x<<16)*qv[0] + __uint_as_float(hv.x & 0xffff0000u)*qv[1]
                + __uint_as_float(hv.y<<16)*qv[2] + __uint_as_float(hv.y & 0xffff0000u)*qv[3]
                + __uint_as_float(hv.z<<16)*qv[4] + __uint_as_float(hv.z & 0xffff0000u)*qv[5]
                + __uint_as_float(hv.w<<16)*qv[6] + __uint_as_float(hv.w & 0xffff0000u)*qv[7];
        const float* Sp = S + p*64;
        #pragma unroll
        for (int s2=0;s2<16;++s2){
            float4 sv = *((const float4*)(Sp + 4*s2));
            a += sv.x*qv[8+4*s2] + sv.y*qv[9+4*s2] + sv.z*qv[10+4*s2] + sv.w*qv[11+4*s2];
        }
        elog[qi*P_ + p] = a;
    }
    __syncthreads();
    // ---- softmax (max, exp, sum) per query
    {
        int qi = tid >> 7, lt = tid & 127;
        float mx = -1e30f;
        for (int p = lt; p < P_; p += 128) mx = fmaxf(mx, elog[qi*P_ + p]);
        for (int off=32; off; off>>=1) mx = fmaxf(mx, __shfl_down(mx, off));
        if ((tid & 63) == 0) red[tid>>6] = mx;
        __syncthreads();
        if (tid < 4) red[16+tid] = fmaxf(red[2*tid], red[2*tid+1]);
        __syncthreads();
        mx = red[16+qi];
        float sm = 0.f;
        for (int p = lt; p < P_; p += 128){ float e = expf(elog[qi*P_ + p]-mx); elog[qi*P_ + p] = e; sm += e; }
        for (int off=32; off; off>>=1) sm += __shfl_down(sm, off);
        if ((tid & 63) == 0) red[8 + (tid>>6)] = sm;
        __syncthreads();
        if (tid < 4) red[24+tid] = red[8+2*tid] + red[8+2*tid+1];
        __syncthreads();
    }
    // ---- ans = softmax(A) @ V : vectorized, 4-lane p-split + shfl reduce
    if (tid < 240){
        int g = tid >> 2;            // 60 groups: qi 0..3 x vb 0..14 (8 channels each)
        int qi = g / 15, vb = g % 15;
        int pc = tid & 3;
        float ac[8] = {0,0,0,0,0,0,0,0};
        const unsigned short* hb8 = hrb + 8 + vb*8;
        for (int p = pc*135; p < pc*135+135; ++p){
            float e = elog[qi*P_ + p];
            uint4 hv = *((const uint4*)(hb8 + (size_t)p*128));
            ac[0] += e*__uint_as_float(hv.x<<16);
            ac[1] += e*__uint_as_float(hv.x & 0xffff0000u);
            ac[2] += e*__uint_as_float(hv.y<<16);
            ac[3] += e*__uint_as_float(hv.y & 0xffff0000u);
            ac[4] += e*__uint_as_float(hv.z<<16);
            ac[5] += e*__uint_as_float(hv.z & 0xffff0000u);
            ac[6] += e*__uint_as_float(hv.w<<16);
            ac[7] += e*__uint_as_float(hv.w & 0xffff0000u);
        }
        #pragma unroll
        for (int j=0;j<8;++j){ ac[j] += __shfl_down(ac[j],2); ac[j] += __shfl_down(ac[j],1); }
        if ((tid&3)==0){
            float inv2 = 1.f/red[24+qi];
            #pragma unroll
            for (int j=0;j<8;++j) ansv[qi*184 + vb*8 + j] = ac[j]*inv2;
        }
    } else if (tid < 496){
        int u = tid - 240;
        int g = u >> 2;              // 64 groups: qi 0..3 x vb4 0..15 (4 floats of S each)
        int qi = g >> 4, vb4 = g & 15;
        int pc = u & 3;
        float ac[4] = {0,0,0,0};
        const float* Sp = S + vb4*4;
        for (int p = pc*135; p < pc*135+135; ++p){
            float e = elog[qi*P_ + p];
            float4 sv = *((const float4*)(Sp + (size_t)p*64));
            ac[0]+=e*sv.x; ac[1]+=e*sv.y; ac[2]+=e*sv.z; ac[3]+=e*sv.w;
        }
        #pragma unroll
        for (int j=0;j<4;++j){ ac[j] += __shfl_down(ac[j],2); ac[j] += __shfl_down(ac[j],1); }
        if ((tid&3)==0){
            float inv2 = 1.f/red[24+qi];
            #pragma unroll
            for (int j=0;j<4;++j) ansv[qi*184 + 120 + vb4*4 + j] = ac[j]*inv2;
        }
    }
    __syncthreads();
    // ---- hid = relu(ansv @ aw1 + ab1)
    {
        float a0=ab1[tid], a1=0.f, a2=0.f, a3=0.f;
        for (int i4=0;i4<261;++i4){
            ushort4 w = *((const ushort4*)(pa1 + (size_t)((i4<<9)+tid)*4));
            float4 av = *((const float4*)(ansv + i4*4));
            a0 += av.x*bfu(w.x); a1 += av.y*bfu(w.y);
            a2 += av.z*bfu(w.z); a3 += av.w*bfu(w.w);
        }
        hid[tid] = fmaxf((a0+a1)+(a2+a3), 0.f);
    }
    if (tid < 256) hs2[tid] = hs[tid]*m;
    __syncthreads();
    // ---- cis = hid @ aw2 + ab2
    if (tid < 256){
        float a0=ab2[tid],a1=0.f,a2=0.f,a3=0.f;
        for (int i4=0;i4<128;++i4){
            ushort4 w = *((const ushort4*)(pa2 + (size_t)((i4<<8)+tid)*4));
            float4 hv = *((const float4*)(hid + i4*4));
            a0 += hv.x*bfu(w.x); a1 += hv.y*bfu(w.y);
            a2 += hv.z*bfu(w.z); a3 += hv.w*bfu(w.w);
        }
        cis[tid] = (a0+a1)+(a2+a3);
    }
    __syncthreads();
    // ---- gates = cis @ w_ih^T + hs2 @ w_hh^T + b
    for (int g = tid; g < 1024; g += 512){
        float a0=bih[g]+bhh[g], a1=0.f, a2=0.f, a3=0.f;
        for (int i4=0;i4<64;++i4){
            ushort4 wi = *((const ushort4*)(pih + (size_t)((i4<<10)+g)*4));
            ushort4 wh = *((const ushort4*)(phh + (size_t)((i4<<10)+g)*4));
            float4 cv = *((const float4*)(cis + i4*4));
            float4 hv = *((const float4*)(hs2 + i4*4));
            a0 += cv.x*bfu(wi.x) + hv.x*bfu(wh.x);
            a1 += cv.y*bfu(wi.y) + hv.y*bfu(wh.y);
            a2 += cv.z*bfu(wi.z) + hv.z*bfu(wh.z);
            a3 += cv.w*bfu(wi.w) + hv.w*bfu(wh.w);
        }
        gb[g] = (a0+a1)+(a2+a3);
    }
    __syncthreads();
    if (tid < 256){
        float gi = gb[tid], gf = gb[256+tid], gg = gb[512+tid], go = gb[768+tid];
        float cold = cs[tid]*m;
        float cn = sigm(gf)*cold + sigm(gi)*tanhf(gg);
        float hn = sigm(go)*tanhf(cn);
        csb[b*256+tid] = cn;
        hsb[b*256+tid] = hn;
        outs[(tc*B_+b)*256+tid] = hn;
    }
}

// ---------------- heads
__global__ __launch_bounds__(64) void finalk(const float* __restrict__ outs,
                                             const float* __restrict__ pw, const float* __restrict__ pb,
                                             const float* __restrict__ vw, const float* __restrict__ vb,
                                             float* __restrict__ dout){
    int row = blockIdx.x, tid = threadIdx.x;
    __shared__ float os[256];
    __shared__ float lg[NA];
    for (int i=tid; i<256; i+=64) os[i] = outs[row*256+i];
    __syncthreads();
    if (tid < NA){
        float a = pb[tid];
        for (int i=0;i<256;++i) a += os[i]*pw[i*NA+tid];
        lg[tid] = a;
        dout[row*NA + tid] = a;
    } else if (tid == 32){
        float a = vb[0];
        for (int i=0;i<256;++i) a += os[i]*vw[i];
        dout[9216 + row] = a;
    }
    __syncthreads();
    if (tid == 0){
        int am = 0; float bv = lg[0];
        for (int j=1;j<NA;++j) if (lg[j] > bv){ bv = lg[j]; am = j; }
        dout[9728 + row] = (float)am;
    }
}

extern "C" void kernel_launch(void* const* d_in, const int* in_sizes, int n_in,
                              void* d_out, int out_size, void* d_ws, size_t ws_size,
                              hipStream_t stream) {
    const float* frame   = (const float*)d_in[0];
    const unsigned char* done = (const unsigned char*)d_in[1];
    const int*   lact    = (const int*)d_in[2];
    const float* reward  = (const float*)d_in[3];
    const float* core_h0 = (const float*)d_in[4];
    const float* core_c0 = (const float*)d_in[5];
    const float* conv_h0 = (const float*)d_in[6];
    const float* conv_c0 = (const float*)d_in[7];
    const float* cnn_w1  = (const float*)d_in[8];
    const float* cnn_b1  = (const float*)d_in[9];
    const float* cnn_w2  = (const float*)d_in[10];
    const float* cnn_b2  = (const float*)d_in[11];
    const float* lstm_w  = (const float*)d_in[12];
    const float* lstm_b  = (const float*)d_in[13];
    const float* qw1 = (const float*)d_in[14]; const float* qb1 = (const float*)d_in[15];
    const float* qw2 = (const float*)d_in[16]; const float* qb2 = (const float*)d_in[17];
    const float* qw3 = (const float*)d_in[18]; const float* qb3 = (const float*)d_in[19];
    const float* aw1 = (const float*)d_in[20]; const float* ab1 = (const float*)d_in[21];
    const float* aw2 = (const float*)d_in[22]; const float* ab2 = (const float*)d_in[23];
    const float* w_ih = (const float*)d_in[24]; const float* w_hh = (const float*)d_in[25];
    const float* b_ih = (const float*)d_in[26]; const float* b_hh = (const float*)d_in[27];
    const float* pw = (const float*)d_in[28]; const float* pb = (const float*)d_in[29];
    const float* vw = (const float*)d_in[30]; const float* vb = (const float*)d_in[31];

    float* ws = (float*)d_ws;
    float* dout = (float*)d_out;

    // ws layout (float offsets). c1pad is transient: consumed by c2mfma, then
    // hreA/apack/weight-packs are written into that range (after c2mfma in stream order).
    unsigned short* xpad   = (unsigned short*)ws;                         // 20,971,520 u16
    unsigned short* c1pad  = (unsigned short*)(ws + 10485760);            // 38,535,168 u16 (transient)
    unsigned short* hreA   = (unsigned short*)(ws + 10485760);            // 35,389,440 u16
    unsigned short* apack  = (unsigned short*)(ws + 28180480);            // 1,572,864 u16
    unsigned short* wpk    = (unsigned short*)(ws + 28966912);            // packed core weights (bf16)
    unsigned short* pq1 = wpk;            // 32768
    unsigned short* pq2 = wpk + 32768;    // 36864
    unsigned short* pq3 = wpk + 69632;    // 82944
    unsigned short* pa1 = wpk + 152576;   // 534528
    unsigned short* pa2 = wpk + 687104;   // 131072
    unsigned short* pih = wpk + 818176;   // 262144
    unsigned short* phh = wpk + 1080320;  // ends 1,342,464
    unsigned short* hpad0  = (unsigned short*)(ws + 29753344);            // 1,310,720 u16
    unsigned short* apack2 = (unsigned short*)(ws + 30408704);            // 32,768 u16
    unsigned short* hpad1  = (unsigned short*)(ws + 30425088);            // 1,310,720 u16
    float* hsb   = ws + 31080448;      // 4,096
    float* csb   = ws + 31084544;      // 4,096
    float* vh    = ws + 34881536;      // 1,105,920
    float* vc    = ws + 35987456;      // 1,105,920
    float* S     = ws + 37093376;      // 34,560
    float* outs  = ws + 37127936;      // 131,072  (total < 37,263,104 floats = 149 MB)

    // zero padded planes (interiors overwritten)
    hipMemsetAsync(xpad,  0, (size_t)20971520*2, stream);
    hipMemsetAsync(c1pad, 0, (size_t)38535168*2, stream);

    // CNN
    apack2k<<<128, 256, 0, stream>>>(cnn_w2, apack2);
    conv1k<<<512*52, 256, 0, stream>>>(frame, cnn_w1, cnn_b1, c1pad);
    c2mfma<<<2560, 256, 0, stream>>>(c1pad, apack2, cnn_b2, xpad);

    // c1pad is dead from here on — its range is reused below
    hipMemsetAsync(hpad0, 0, (size_t)1310720*2, stream);
    hipMemsetAsync(hpad1, 0, (size_t)1310720*2, stream);
    sbasisk<<<135, 256, 0, stream>>>(S);
    apackk<<<6144, 256, 0, stream>>>(lstm_w, apack);
    // core-weight bf16 x4 packs (2.68 MB total -> cache-resident in core blocks)
    packw4k<<<128,  256, 0, stream>>>(qw1, pq1, 256, 128);
    packw4k<<<144,  256, 0, stream>>>(qw2, pq2, 128, 288);
    packw4k<<<324,  256, 0, stream>>>(qw3, pq3, 288, 288);
    packw4k<<<2088, 256, 0, stream>>>(aw1, pa1, 1043, 512);
    packw4k<<<512,  256, 0, stream>>>(aw2, pa2, 512, 256);
    packt4k<<<1024, 256, 0, stream>>>(w_ih, pih, 256, 1024);
    packt4k<<<1024, 256, 0, stream>>>(w_hh, phh, 256, 1024);
    h0packk<<<4320, 256, 0, stream>>>(conv_h0, hpad0);
    hipMemcpyAsync(vc,  conv_c0, (size_t)16*128*540*sizeof(float), hipMemcpyDeviceToDevice, stream);
    hipMemcpyAsync(hsb, core_h0, (size_t)16*256*sizeof(float), hipMemcpyDeviceToDevice, stream);
    hipMemcpyAsync(csb, core_c0, (size_t)16*256*sizeof(float), hipMemcpyDeviceToDevice, stream);

    // software-pipelined loop: vis step t  ||  core step t-1  (33 dispatches)
    for (int t = 0; t <= T_; ++t){
        gvck<<<304, 512, 0, stream>>>(xpad, (t&1)?hpad1:hpad0, (t&1)?hpad0:hpad1,
                                      apack, lstm_b, done, vh, vc, hreA,
                                      S, pq1,qb1,pq2,qb2,pq3,qb3,
                                      pa1,ab1,pa2,ab2, pih,phh,b_ih,b_hh,
                                      reward, lact, hsb, csb, outs, t);
    }

    finalk<<<512, 64, 0, stream>>>(outs, pw, pb, vw, vb, dout);

    hipMemcpyAsync(dout + 10240,   outs + (size_t)31*B_*256, (size_t)16*256*sizeof(float), hipMemcpyDeviceToDevice, stream);
    hipMemcpyAsync(dout + 14336,   csb, (size_t)16*256*sizeof(float), hipMemcpyDeviceToDevice, stream);
    hipMemcpyAsync(dout + 18432,   vh,  (size_t)16*128*540*sizeof(float), hipMemcpyDeviceToDevice, stream);
    hipMemcpyAsync(dout + 1124352, vc,  (size_t)16*128*540*sizeof(float), hipMemcpyDeviceToDevice, stream);
}

// Round 4
// 4928.532 us; speedup vs baseline: 2.0577x; 1.1258x over previous
//
#include <hip/hip_runtime.h>
#include <math.h>

#define T_ 32
#define B_ 16
#define NA 18
#define P_ 540   // 27*20

typedef __attribute__((ext_vector_type(8)))  short short8;
typedef __attribute__((ext_vector_type(16))) float f32x16;

__device__ __forceinline__ float sigm(float x){ return 1.0f/(1.0f+expf(-x)); }
__device__ __forceinline__ unsigned short f2bf(float f){
    unsigned u = __float_as_uint(f);
    u += 0x7fff + ((u>>16)&1u);
    return (unsigned short)(u>>16);
}
__device__ __forceinline__ float bfu(unsigned short u){ return __uint_as_float(((unsigned)u)<<16); }

// ---------------- conv1: (512,3,210,160) -> c1pad bf16 [512][32][56][42], k8 s4 padH(1,1) W(2,2)
// 2 output rows per block: 12-row tile, 80 FMA per weight-load pair.
__global__ __launch_bounds__(256) void conv1k(const float* __restrict__ frame,
                                              const float* __restrict__ w,
                                              const float* __restrict__ bias,
                                              unsigned short* __restrict__ c1pad){
    __shared__ float tile[6048];  // 3ch * 12rows * 168cols
    int bid = blockIdx.x;
    int n = bid / 26, oh = (bid % 26)*2;
    int tid = threadIdx.x;
    const float* fb = frame + (size_t)n*3*210*160;
    for (int s = tid; s < 6048; s += 256){
        int col = s % 168;
        int row = (s/168) % 12;
        int ic  = s / 2016;
        int iy = oh*4 - 1 + row;
        int ix = col - 2;
        float v = 0.f;
        if (iy >= 0 && iy < 210 && ix >= 0 && ix < 160) v = fb[ic*33600 + iy*160 + ix];
        tile[s] = v;
    }
    __syncthreads();
    int oc = tid & 31, grp = tid >> 5;      // grp 0..7 -> ow = grp*5..grp*5+4
    float acc[10] = {0.f,0.f,0.f,0.f,0.f,0.f,0.f,0.f,0.f,0.f};
    const float* wb = w + oc*192;
    for (int ic=0; ic<3; ++ic){
        #pragma unroll
        for (int kh=0; kh<8; ++kh){
            const float* wr = wb + ic*64 + kh*8;
            float4 w0 = *((const float4*)wr);
            float4 w1 = *((const float4*)(wr+4));
            const float* rowA = tile + ic*2016 + kh*168 + grp*20;
            float r[24];
            *((float4*)(r+ 0)) = *((const float4*)(rowA+ 0));
            *((float4*)(r+ 4)) = *((const float4*)(rowA+ 4));
            *((float4*)(r+ 8)) = *((const float4*)(rowA+ 8));
            *((float4*)(r+12)) = *((const float4*)(rowA+12));
            *((float4*)(r+16)) = *((const float4*)(rowA+16));
            *((float4*)(r+20)) = *((const float4*)(rowA+20));
            #pragma unroll
            for (int o=0;o<5;++o){
                acc[o] += r[o*4+0]*w0.x + r[o*4+1]*w0.y + r[o*4+2]*w0.z + r[o*4+3]*w0.w
                        + r[o*4+4]*w1.x + r[o*4+5]*w1.y + r[o*4+6]*w1.z + r[o*4+7]*w1.w;
            }
            const float* rowB = rowA + 672;   // +4 input rows
            *((float4*)(r+ 0)) = *((const float4*)(rowB+ 0));
            *((float4*)(r+ 4)) = *((const float4*)(rowB+ 4));
            *((float4*)(r+ 8)) = *((const float4*)(rowB+ 8));
            *((float4*)(r+12)) = *((const float4*)(rowB+12));
            *((float4*)(r+16)) = *((const float4*)(rowB+16));
            *((float4*)(r+20)) = *((const float4*)(rowB+20));
            #pragma unroll
            for (int o=0;o<5;++o){
                acc[5+o] += r[o*4+0]*w0.x + r[o*4+1]*w0.y + r[o*4+2]*w0.z + r[o*4+3]*w0.w
                          + r[o*4+4]*w1.x + r[o*4+5]*w1.y + r[o*4+6]*w1.z + r[o*4+7]*w1.w;
            }
        }
    }
    float bi = bias[oc];
    unsigned short* ob = c1pad + ((size_t)(n*32 + oc)*56 + oh+2)*42 + 1;
    #pragma unroll
    for (int o=0;o<5;++o) ob[grp*5+o] = f2bf(acc[o] + bi);
    ob += 42;
    #pragma unroll
    for (int o=0;o<5;++o) ob[grp*5+o] = f2bf(acc[5+o] + bi);
}

// ---------------- conv2 A-pack: cnn_w2 (64,32,4,4) -> apack2[32 ic][2 mt][64 lane][8] bf16
__global__ void apack2k(const float* __restrict__ w2, unsigned short* __restrict__ ap){
    int idx = blockIdx.x*256 + threadIdx.x;
    if (idx >= 32768) return;
    int j = idx & 7;
    int lane = (idx>>3) & 63;
    int mt = (idx>>9) & 1;
    int ic = idx >> 10;
    int k = ((lane>>5)<<3) + j;          // kh*4+kw
    int oc = mt*32 + (lane & 31);
    ap[idx] = f2bf(w2[((oc*32 + ic)<<4) + k]);
}

// ---------------- conv2 MFMA: c1pad bf16 -> xpad bf16 [512][64][640], k4 s2 padH(2,2) W(1,1)
__global__ __launch_bounds__(256) void c2mfma(const unsigned short* __restrict__ c1pad,
                                              const unsigned short* __restrict__ apack2,
                                              const float* __restrict__ bias,
                                              unsigned short* __restrict__ xpad){
    __shared__ unsigned short p2[2][3072];   // [n 128][stride 24]
    __shared__ float bsm[64];
    int bid = blockIdx.x;
    int s = bid / 5;
    int n0 = (bid % 5) * 128;
    int tid = threadIdx.x;
    int wave = tid >> 6, lane = tid & 63;
    int khalf = (lane>>5) << 3;
    if (tid < 64) bsm[tid] = bias[tid];
    const unsigned short* cb = c1pad + (size_t)s*32*2352;

    int soff[8], swaddr[8];
    #pragma unroll
    for (int q=0;q<8;++q){
        int idx = q*256 + tid;
        int n = idx & 127, k = idx >> 7;
        int p = n0 + n; if (p > 539) p = 539;
        soff[q] = ((p/20)*2 + (k>>2))*42 + (p%20)*2 + (k&3);
        swaddr[q] = n*24 + k;
    }
    #pragma unroll
    for (int q=0;q<8;++q) p2[0][swaddr[q]] = cb[soff[q]];
    unsigned short rv[8];
    #pragma unroll
    for (int q=0;q<8;++q) rv[q] = cb[2352 + soff[q]];

    int mt = wave >> 1, ntb = (wave & 1) * 2;
    short8 acur = *((const short8*)(apack2 + ((size_t)mt*64 + lane)*8));
    short8 anxt;
    f32x16 acc[2];
    #pragma unroll
    for (int jj=0;jj<2;++jj)
        #pragma unroll
        for (int rg=0;rg<16;++rg) acc[jj][rg] = 0.f;
    __syncthreads();

    for (int c=0; c<32; ++c){
        int buf = c & 1;
        if (c < 31){
            #pragma unroll
            for (int q=0;q<8;++q) p2[buf^1][swaddr[q]] = rv[q];
        }
        if (c < 30){
            const unsigned short* src = cb + (size_t)(c+2)*2352;
            #pragma unroll
            for (int q=0;q<8;++q) rv[q] = src[soff[q]];
        }
        if (c < 31) anxt = *((const short8*)(apack2 + ((size_t)((c+1)*2 + mt)*64 + lane)*8));
        #pragma unroll
        for (int jj=0;jj<2;++jj){
            int n = (ntb+jj)*32 + (lane & 31);
            short8 bf = *((const short8*)(&p2[buf][n*24 + khalf]));
            acc[jj] = __builtin_amdgcn_mfma_f32_32x32x16_bf16(acur, bf, acc[jj], 0, 0, 0);
        }
        acur = anxt;
        __syncthreads();
    }
    #pragma unroll
    for (int jj=0;jj<2;++jj){
        int pos = n0 + (ntb+jj)*32 + (lane & 31);
        if (pos >= 540) continue;
        int y = pos/20, x = pos%20;
        unsigned short* op = xpad + (size_t)s*64*640 + (y+1)*22 + x + 1;
        #pragma unroll
        for (int rg=0; rg<16; ++rg){
            int oc = mt*32 + (rg & 3) + 8*(rg>>2) + 4*(lane>>5);
            op[(size_t)oc*640] = f2bf(acc[jj][rg] + bsm[oc]);
        }
    }
}

// ---------------- spatial basis S[540][64]
__global__ void sbasisk(float* __restrict__ S){
    int idx = blockIdx.x*256 + threadIdx.x;
    if (idx >= P_*64) return;
    int s = idx & 63, p = idx >> 6;
    int y = p/20, x = p%20;
    int u = s >> 3, v = s & 7;
    double a  = cos((double)((y+1)*(u+1)) * M_PI / 27.0);
    double bb = cos((double)((x+1)*(v+1)) * M_PI / 20.0);
    S[idx] = (float)(a*bb);
}

// ---------------- weight pack: f32 [R][C] -> bf16 [(R+3)/4][C][4]  (pad rows -> 0)
__global__ void packw4k(const float* __restrict__ in, unsigned short* __restrict__ out, int R, int C){
    int idx = blockIdx.x*256 + threadIdx.x;
    int r4cnt = (R+3)>>2;
    if (idx >= r4cnt*C*4) return;
    int j = idx & 3;
    int rc = idx >> 2;
    int c = rc % C;
    int r = (rc / C)*4 + j;
    out[idx] = (r < R) ? f2bf(in[(size_t)r*C + c]) : (unsigned short)0;
}
// ---------------- weight pack (transposed input): f32 [C][R] -> bf16 [(R+3)/4][C][4]
__global__ void packt4k(const float* __restrict__ in, unsigned short* __restrict__ out, int R, int C){
    int idx = blockIdx.x*256 + threadIdx.x;
    int r4cnt = (R+3)>>2;
    if (idx >= r4cnt*C*4) return;
    int j = idx & 3;
    int rc = idx >> 2;
    int c = rc % C;
    int r = (rc / C)*4 + j;
    out[idx] = (r < R) ? f2bf(in[(size_t)c*R + r]) : (unsigned short)0;
}

// ---------------- gates A-pack (tap-wise): lstm_w (512,192,3,3) ->
// ap[tap 9][chunk 12][16 mt][64 lane][8] bf16, K = 192 channels (no zero padding)
__global__ void apack9k(const float* __restrict__ lw, unsigned short* __restrict__ ap){
    int idx = blockIdx.x*256 + threadIdx.x;
    if (idx >= 884736) return;
    int j = idx & 7;
    int lane = (idx>>3) & 63;
    int mt = (idx>>9) & 15;
    int f  = idx >> 13;            // 0..107 = tap*12 + c
    int tap = f / 12, c = f % 12;
    int ch = c*16 + ((lane>>5)<<3) + j;
    int oc = mt*32 + (lane & 31);
    ap[idx] = f2bf(lw[(size_t)oc*1728 + ch*9 + tap]);
}

// ---------------- pack conv_h0 fp32 -> hpad bf16 interior
__global__ void h0packk(const float* __restrict__ h0, unsigned short* __restrict__ hpad){
    int idx = blockIdx.x*256 + threadIdx.x;
    if (idx >= 16*128*540) return;
    int plane = idx / 540, p = idx % 540;
    hpad[(size_t)plane*640 + (p/20+1)*22 + (p%20) + 1] = f2bf(h0[idx]);
}

// =====================================================================================
// gvck: ONE dispatch per t does BOTH pipeline stages concurrently:
//   blocks 0..287  : vis ConvLSTM step t — tap-wise MFMA conv (stage x+h window once in
//                    LDS channel-major, 9 taps x 12 K-chunks, ONE barrier) + fused pointwise
//   blocks 288..303: core recurrence step t-1 (reads hreA[t-1] from PREVIOUS dispatch)
// =====================================================================================
__global__ __launch_bounds__(512) void gvck(const unsigned short* __restrict__ xpad,
                                            const unsigned short* __restrict__ hrd,
                                            unsigned short* __restrict__ hwr,
                                            const unsigned short* __restrict__ apack,
                                            const float* __restrict__ lb,
                                            const unsigned char* __restrict__ done,
                                            float* __restrict__ vh, float* __restrict__ vc,
                                            unsigned short* __restrict__ hreA,
                                            const float* __restrict__ S,
                                            const unsigned short* __restrict__ pq1, const float* __restrict__ qb1,
                                            const unsigned short* __restrict__ pq2, const float* __restrict__ qb2,
                                            const unsigned short* __restrict__ pq3, const float* __restrict__ qb3,
                                            const unsigned short* __restrict__ pa1, const float* __restrict__ ab1,
                                            const unsigned short* __restrict__ pa2, const float* __restrict__ ab2,
                                            const unsigned short* __restrict__ pih, const unsigned short* __restrict__ phh,
                                            const float* __restrict__ bih, const float* __restrict__ bhh,
                                            const float* __restrict__ reward, const int* __restrict__ lact,
                                            float* __restrict__ hsb, float* __restrict__ csb,
                                            float* __restrict__ outs,
                                            int t){
    __shared__ __align__(16) unsigned char smraw[65536];
    int bid = blockIdx.x;
    int tid = threadIdx.x;

    if (bid < 288){
        // ---------------- vis ConvLSTM step t ----------------
        if (t >= T_) return;
        unsigned short* sm = (unsigned short*)smraw;   // [132 pos][200 ch] staging, 52.8 KB
        float* gsm = (float*)smraw;                    // [4][64][64] f32 after K-loop (64 KB)
        int b  = bid % 16;
        int r  = bid / 16;
        int nb = r % 9;
        int mh = r / 9;
        int wave = tid >> 6, lane = tid & 63;
        int khalf = (lane>>5) << 3;
        int n0 = nb * 64;
        int y0 = n0 / 20;                              // window base padded row
        bool dn = done[t*B_ + b];

        const unsigned short* xb = xpad + ((size_t)(t*B_ + b))*64*640;
        const unsigned short* hb = hrd + (size_t)b*128*640;

        // stage 192 ch x 6 padded rows (22 u16 each) -> sm[pos][ch], pos = r6*22+c
        for (int rr = tid; rr < 1152; rr += 512){
            int ch = rr / 6, r6 = rr % 6;
            int prow = y0 + r6;
            unsigned short* dst = sm + (r6*22)*200 + ch;
            if (prow <= 28 && !(dn && ch >= 64)){
                const unsigned short* srcp = (ch < 64) ? (xb + ch*640 + prow*22)
                                                       : (hb + (ch-64)*640 + prow*22);
                const unsigned int* s32 = (const unsigned int*)srcp;
                #pragma unroll
                for (int c2=0;c2<11;++c2){
                    unsigned int v = s32[c2];
                    dst[(2*c2)*200]   = (unsigned short)(v & 0xffffu);
                    dst[(2*c2+1)*200] = (unsigned short)(v >> 16);
                }
            } else {
                #pragma unroll
                for (int c2=0;c2<22;++c2) dst[c2*200] = 0;
            }
        }

        // wave -> (gate, half): mt = gate*4 + mh*2 + half
        int mt = (wave>>1)*4 + mh*2 + (wave&1);
        int sb[2];
        #pragma unroll
        for (int jj=0;jj<2;++jj){
            int p = n0 + jj*32 + (lane & 31); if (p > 539) p = 539;
            sb[jj] = ((p/20) - y0)*22 + (p%20);
        }
        f32x16 acc[2];
        #pragma unroll
        for (int jj=0;jj<2;++jj)
            #pragma unroll
            for (int rg=0;rg<16;++rg) acc[jj][rg] = 0.f;
        __syncthreads();

        // K-loop: 9 taps x 12 chunks of K=16 channels; no barriers (LDS read-only)
        for (int tap=0; tap<9; ++tap){
            int tadd = (tap/3)*22 + (tap%3);
            #pragma unroll
            for (int c=0;c<12;++c){
                short8 af = *((const short8*)(apack + ((size_t)((tap*12+c)*16 + mt)*64 + lane)*8));
                int ch0 = c*16 + khalf;
                short8 b0 = *((const short8*)(&sm[(sb[0]+tadd)*200 + ch0]));
                short8 b1 = *((const short8*)(&sm[(sb[1]+tadd)*200 + ch0]));
                acc[0] = __builtin_amdgcn_mfma_f32_32x32x16_bf16(af, b0, acc[0], 0, 0, 0);
                acc[1] = __builtin_amdgcn_mfma_f32_32x32x16_bf16(af, b1, acc[1], 0, 0, 0);
            }
        }
        __syncthreads();   // staging reads done -> safe to overwrite with gsm

        // stage gates to LDS: gsm[gate][c_loc][p_loc]
        int g8 = wave >> 1, ih = wave & 1;
        #pragma unroll
        for (int j=0;j<2;++j){
            int p_loc = j*32 + (lane & 31);
            #pragma unroll
            for (int rg=0; rg<16; ++rg){
                int c_loc = ih*32 + 4*(lane>>5) + (rg & 3) + 8*(rg>>2);
                gsm[g8*4096 + c_loc*64 + p_loc] = acc[j][rg];
            }
        }
        __syncthreads();

        // fused LSTM pointwise: 512 threads x 8 elements over 64c x 64p
        {
            int p_loc = tid & 63, c0 = tid >> 6;
            int pg = n0 + p_loc;
            if (pg < 540){
                float m = dn ? 0.f : 1.f;
                int y = pg/20, x = pg%20;
                #pragma unroll
                for (int e=0;e<8;++e){
                    int c_loc = c0*8 + e;
                    int cg = mh*64 + c_loc;
                    float gi = gsm[        c_loc*64 + p_loc] + lb[      cg];
                    float gf = gsm[ 4096 + c_loc*64 + p_loc] + lb[128 + cg];
                    float go = gsm[ 8192 + c_loc*64 + p_loc] + lb[256 + cg];
                    float gg = gsm[12288 + c_loc*64 + p_loc] + lb[384 + cg];
                    size_t idx = ((size_t)b*128 + cg)*540 + pg;
                    float cold = vc[idx] * m;
                    float cn = sigm(gf)*cold + sigm(gi)*tanhf(gg);
                    float hn = sigm(go)*tanhf(cn);
                    vc[idx] = cn;
                    if (t == T_-1) vh[idx] = hn;
                    hwr[((size_t)b*128 + cg)*640 + (y+1)*22 + x + 1] = f2bf(hn);
                    int flat = cg*540 + pg;
                    int pos = (flat/2560)*20 + (flat/128)%20;
                    int ch  = flat & 127;
                    hreA[((size_t)(t*B_ + b)*540 + pos)*128 + ch] = f2bf(hn);
                }
            }
        }
        return;
    }

    // ---------------- core recurrence step tc = t-1 ----------------
    if (t == 0) return;
    int tc = t - 1;
    int b = bid - 288;
    float* fs = (float*)smraw;
    float* hs   = fs;          // 256
    float* cs   = fs + 256;    // 256
    float* hs2  = fs + 512;    // 256
    float* q1   = fs + 768;    // 128
    float* q2   = fs + 896;    // 288
    float* q3   = fs + 1184;   // 288
    float* elog = fs + 1472;   // 4*540
    float* red  = fs + 3632;   // 32
    float* ansv = fs + 3664;   // 1056
    float* hid  = fs + 4720;   // 512
    float* cis  = fs + 5232;   // 256
    float* gb   = fs + 5488;   // 1024  (ends 6512 floats = 26 KB)

    if (tid < 256){ hs[tid] = hsb[b*256+tid]; cs[tid] = csb[b*256+tid]; }
    if (tid >= 256 && tid < 269) ansv[1043 + (tid-256)] = 0.f;   // pad rows of aw1 -> 0
    __syncthreads();

    float m = done[tc*B_+b] ? 0.f : 1.f;
    // ---- q1 = relu(hs @ qw1 + qb1)
    if (tid < 128){
        float a0=0.f,a1=0.f,a2=0.f,a3=0.f;
        for (int i4=0;i4<64;++i4){
            ushort4 w = *((const ushort4*)(pq1 + (size_t)((i4<<7)+tid)*4));
            float4 h4 = *((const float4*)(hs + i4*4));
            a0 += h4.x*bfu(w.x); a1 += h4.y*bfu(w.y);
            a2 += h4.z*bfu(w.z); a3 += h4.w*bfu(w.w);
        }
        q1[tid] = fmaxf(qb1[tid] + ((a0+a1)+(a2+a3)), 0.f);
    }
    __syncthreads();
    // ---- q2 = relu(q1 @ qw2 + qb2)
    if (tid < 288){
        float a0=0.f,a1=0.f,a2=0.f,a3=0.f;
        for (int i4=0;i4<32;++i4){
            ushort4 w = *((const ushort4*)(pq2 + (size_t)(i4*288+tid)*4));
            float4 h4 = *((const float4*)(q1 + i4*4));
            a0 += h4.x*bfu(w.x); a1 += h4.y*bfu(w.y);
            a2 += h4.z*bfu(w.z); a3 += h4.w*bfu(w.w);
        }
        q2[tid] = fmaxf(qb2[tid] + ((a0+a1)+(a2+a3)), 0.f);
    }
    __syncthreads();
    // ---- q3 = q2 @ qw3 + qb3
    if (tid < 288){
        float a0=0.f,a1=0.f,a2=0.f,a3=0.f;
        for (int i4=0;i4<72;++i4){
            ushort4 w = *((const ushort4*)(pq3 + (size_t)(i4*288+tid)*4));
            float4 h4 = *((const float4*)(q2 + i4*4));
            a0 += h4.x*bfu(w.x); a1 += h4.y*bfu(w.y);
            a2 += h4.z*bfu(w.z); a3 += h4.w*bfu(w.w);
        }
        float a = qb3[tid] + ((a0+a1)+(a2+a3));
        q3[tid] = a;
        ansv[736+tid] = a;
    }
    if (tid == 0){ float r = reward[tc*B_+b]; ansv[1024] = fminf(1.f,fmaxf(-1.f,r)); }
    if (tid >= 32 && tid < 32+NA) ansv[1025 + tid-32] = (lact[tc*B_+b] == tid-32) ? 1.f : 0.f;
    __syncthreads();

    // ---- attention logits
    const unsigned short* hrb = hreA + (size_t)(tc*B_ + b)*540*128;
    for (int idx = tid; idx < 4*P_; idx += 512){
        int qi = idx / P_, p = idx % P_;
        const unsigned short* hp = hrb + (size_t)p*128;
        uint4 hv = *((const uint4*)hp);
        const float* qv = q3 + qi*72;
        float a = __uint_as_float(hv.x<<16)*qv[0] + __uint_as_float(hv.x & 0xffff0000u)*qv[1]
                + __uint_as_float(hv.y<<16)*qv[2] + __uint_as_float(hv.y & 0xffff0000u)*qv[3]
                + __uint_as_float(hv.z<<16)*qv[4] + __uint_as_float(hv.z & 0xffff0000u)*qv[5]
                + __uint_as_float(hv.w<<16)*qv[6] + __uint_as_float(hv.w & 0xffff0000u)*qv[7];
        const float* Sp = S + p*64;
        #pragma unroll
        for (int s2=0;s2<16;++s2){
            float4 sv = *((const float4*)(Sp + 4*s2));
            a += sv.x*qv[8+4*s2] + sv.y*qv[9+4*s2] + sv.z*qv[10+4*s2] + sv.w*qv[11+4*s2];
        }
        elog[qi*P_ + p] = a;
    }
    __syncthreads();
    // ---- softmax (max, exp, sum) per query
    {
        int qi = tid >> 7, lt = tid & 127;
        float mx = -1e30f;
        for (int p = lt; p < P_; p += 128) mx = fmaxf(mx, elog[qi*P_ + p]);
        for (int off=32; off; off>>=1) mx = fmaxf(mx, __shfl_down(mx, off));
        if ((tid & 63) == 0) red[tid>>6] = mx;
        __syncthreads();
        if (tid < 4) red[16+tid] = fmaxf(red[2*tid], red[2*tid+1]);
        __syncthreads();
        mx = red[16+qi];
        float sm = 0.f;
        for (int p = lt; p < P_; p += 128){ float e = expf(elog[qi*P_ + p]-mx); elog[qi*P_ + p] = e; sm += e; }
        for (int off=32; off; off>>=1) sm += __shfl_down(sm, off);
        if ((tid & 63) == 0) red[8 + (tid>>6)] = sm;
        __syncthreads();
        if (tid < 4) red[24+tid] = red[8+2*tid] + red[8+2*tid+1];
        __syncthreads();
    }
    // ---- ans = softmax(A) @ V : vectorized, 4-lane p-split + shfl reduce
    if (tid < 240){
        int g = tid >> 2;            // 60 groups: qi 0..3 x vb 0..14 (8 channels each)
        int qi = g / 15, vb = g % 15;
        int pc = tid & 3;
        float ac[8] = {0,0,0,0,0,0,0,0};
        const unsigned short* hb8 = hrb + 8 + vb*8;
        for (int p = pc*135; p < pc*135+135; ++p){
            float e = elog[qi*P_ + p];
            uint4 hv = *((const uint4*)(hb8 + (size_t)p*128));
            ac[0] += e*__uint_as_float(hv.x<<16);
            ac[1] += e*__uint_as_float(hv.x & 0xffff0000u);
            ac[2] += e*__uint_as_float(hv.y<<16);
            ac[3] += e*__uint_as_float(hv.y & 0xffff0000u);
            ac[4] += e*__uint_as_float(hv.z<<16);
            ac[5] += e*__uint_as_float(hv.z & 0xffff0000u);
            ac[6] += e*__uint_as_float(hv.w<<16);
            ac[7] += e*__uint_as_float(hv.w & 0xffff0000u);
        }
        #pragma unroll
        for (int j=0;j<8;++j){ ac[j] += __shfl_down(ac[j],2); ac[j] += __shfl_down(ac[j],1); }
        if ((tid&3)==0){
            float inv2 = 1.f/red[24+qi];
            #pragma unroll
            for (int j=0;j<8;++j) ansv[qi*184 + vb*8 + j] = ac[j]*inv2;
        }
    } else if (tid < 496){
        int u = tid - 240;
        int g = u >> 2;              // 64 groups: qi 0..3 x vb4 0..15 (4 floats of S each)
        int qi = g >> 4, vb4 = g & 15;
        int pc = u & 3;
        float ac[4] = {0,0,0,0};
        const float* Sp = S + vb4*4;
        for (int p = pc*135; p < pc*135+135; ++p){
            float e = elog[qi*P_ + p];
            float4 sv = *((const float4*)(Sp + (size_t)p*64));
            ac[0]+=e*sv.x; ac[1]+=e*sv.y; ac[2]+=e*sv.z; ac[3]+=e*sv.w;
        }
        #pragma unroll
        for (int j=0;j<4;++j){ ac[j] += __shfl_down(ac[j],2); ac[j] += __shfl_down(ac[j],1); }
        if ((tid&3)==0){
            float inv2 = 1.f/red[24+qi];
            #pragma unroll
            for (int j=0;j<4;++j) ansv[qi*184 + 120 + vb4*4 + j] = ac[j]*inv2;
        }
    }
    __syncthreads();
    // ---- hid = relu(ansv @ aw1 + ab1)
    {
        float a0=ab1[tid], a1=0.f, a2=0.f, a3=0.f;
        for (int i4=0;i4<261;++i4){
            ushort4 w = *((const ushort4*)(pa1 + (size_t)((i4<<9)+tid)*4));
            float4 av = *((const float4*)(ansv + i4*4));
            a0 += av.x*bfu(w.x); a1 += av.y*bfu(w.y);
            a2 += av.z*bfu(w.z); a3 += av.w*bfu(w.w);
        }
        hid[tid] = fmaxf((a0+a1)+(a2+a3), 0.f);
    }
    if (tid < 256) hs2[tid] = hs[tid]*m;
    __syncthreads();
    // ---- cis = hid @ aw2 + ab2
    if (tid < 256){
        float a0=ab2[tid],a1=0.f,a2=0.f,a3=0.f;
        for (int i4=0;i4<128;++i4){
            ushort4 w = *((const ushort4*)(pa2 + (size_t)((i4<<8)+tid)*4));
            float4 hv = *((const float4*)(hid + i4*4));
            a0 += hv.x*bfu(w.x); a1 += hv.y*bfu(w.y);
            a2 += hv.z*bfu(w.z); a3 += hv.w*bfu(w.w);
        }
        cis[tid] = (a0+a1)+(a2+a3);
    }
    __syncthreads();
    // ---- gates = cis @ w_ih^T + hs2 @ w_hh^T + b
    for (int g = tid; g < 1024; g += 512){
        float a0=bih[g]+bhh[g], a1=0.f, a2=0.f, a3=0.f;
        for (int i4=0;i4<64;++i4){
            ushort4 wi = *((const ushort4*)(pih + (size_t)((i4<<10)+g)*4));
            ushort4 wh = *((const ushort4*)(phh + (size_t)((i4<<10)+g)*4));
            float4 cv = *((const float4*)(cis + i4*4));
            float4 hv = *((const float4*)(hs2 + i4*4));
            a0 += cv.x*bfu(wi.x) + hv.x*bfu(wh.x);
            a1 += cv.y*bfu(wi.y) + hv.y*bfu(wh.y);
            a2 += cv.z*bfu(wi.z) + hv.z*bfu(wh.z);
            a3 += cv.w*bfu(wi.w) + hv.w*bfu(wh.w);
        }
        gb[g] = (a0+a1)+(a2+a3);
    }
    __syncthreads();
    if (tid < 256){
        float gi = gb[tid], gf = gb[256+tid], gg = gb[512+tid], go = gb[768+tid];
        float cold = cs[tid]*m;
        float cn = sigm(gf)*cold + sigm(gi)*tanhf(gg);
        float hn = sigm(go)*tanhf(cn);
        csb[b*256+tid] = cn;
        hsb[b*256+tid] = hn;
        outs[(tc*B_+b)*256+tid] = hn;
    }
}

// ---------------- heads
__global__ __launch_bounds__(64) void finalk(const float* __restrict__ outs,
                                             const float* __restrict__ pw, const float* __restrict__ pb,
                                             const float* __restrict__ vw, const float* __restrict__ vb,
                                             float* __restrict__ dout){
    int row = blockIdx.x, tid = threadIdx.x;
    __shared__ float os[256];
    __shared__ float lg[NA];
    for (int i=tid; i<256; i+=64) os[i] = outs[row*256+i];
    __syncthreads();
    if (tid < NA){
        float a = pb[tid];
        for (int i=0;i<256;++i) a += os[i]*pw[i*NA+tid];
        lg[tid] = a;
        dout[row*NA + tid] = a;
    } else if (tid == 32){
        float a = vb[0];
        for (int i=0;i<256;++i) a += os[i]*vw[i];
        dout[9216 + row] = a;
    }
    __syncthreads();
    if (tid == 0){
        int am = 0; float bv = lg[0];
        for (int j=1;j<NA;++j) if (lg[j] > bv){ bv = lg[j]; am = j; }
        dout[9728 + row] = (float)am;
    }
}

extern "C" void kernel_launch(void* const* d_in, const int* in_sizes, int n_in,
                              void* d_out, int out_size, void* d_ws, size_t ws_size,
                              hipStream_t stream) {
    const float* frame   = (const float*)d_in[0];
    const unsigned char* done = (const unsigned char*)d_in[1];
    const int*   lact    = (const int*)d_in[2];
    const float* reward  = (const float*)d_in[3];
    const float* core_h0 = (const float*)d_in[4];
    const float* core_c0 = (const float*)d_in[5];
    const float* conv_h0 = (const float*)d_in[6];
    const float* conv_c0 = (const float*)d_in[7];
    const float* cnn_w1  = (const float*)d_in[8];
    const float* cnn_b1  = (const float*)d_in[9];
    const float* cnn_w2  = (const float*)d_in[10];
    const float* cnn_b2  = (const float*)d_in[11];
    const float* lstm_w  = (const float*)d_in[12];
    const float* lstm_b  = (const float*)d_in[13];
    const float* qw1 = (const float*)d_in[14]; const float* qb1 = (const float*)d_in[15];
    const float* qw2 = (const float*)d_in[16]; const float* qb2 = (const float*)d_in[17];
    const float* qw3 = (const float*)d_in[18]; const float* qb3 = (const float*)d_in[19];
    const float* aw1 = (const float*)d_in[20]; const float* ab1 = (const float*)d_in[21];
    const float* aw2 = (const float*)d_in[22]; const float* ab2 = (const float*)d_in[23];
    const float* w_ih = (const float*)d_in[24]; const float* w_hh = (const float*)d_in[25];
    const float* b_ih = (const float*)d_in[26]; const float* b_hh = (const float*)d_in[27];
    const float* pw = (const float*)d_in[28]; const float* pb = (const float*)d_in[29];
    const float* vw = (const float*)d_in[30]; const float* vb = (const float*)d_in[31];

    float* ws = (float*)d_ws;
    float* dout = (float*)d_out;

    // ws layout (float offsets). c1pad is transient: consumed by c2mfma, then
    // hreA/apack/weight-packs are written into that range (after c2mfma in stream order).
    unsigned short* xpad   = (unsigned short*)ws;                         // 20,971,520 u16
    unsigned short* c1pad  = (unsigned short*)(ws + 10485760);            // 38,535,168 u16 (transient)
    unsigned short* hreA   = (unsigned short*)(ws + 10485760);            // 35,389,440 u16
    unsigned short* apack  = (unsigned short*)(ws + 28180480);            // 884,736 u16 (tap-wise)
    unsigned short* wpk    = (unsigned short*)(ws + 28966912);            // packed core weights (bf16)
    unsigned short* pq1 = wpk;            // 32768
    unsigned short* pq2 = wpk + 32768;    // 36864
    unsigned short* pq3 = wpk + 69632;    // 82944
    unsigned short* pa1 = wpk + 152576;   // 534528
    unsigned short* pa2 = wpk + 687104;   // 131072
    unsigned short* pih = wpk + 818176;   // 262144
    unsigned short* phh = wpk + 1080320;  // ends 1,342,464
    unsigned short* hpad0  = (unsigned short*)(ws + 29753344);            // 1,310,720 u16
    unsigned short* apack2 = (unsigned short*)(ws + 30408704);            // 32,768 u16
    unsigned short* hpad1  = (unsigned short*)(ws + 30425088);            // 1,310,720 u16
    float* hsb   = ws + 31080448;      // 4,096
    float* csb   = ws + 31084544;      // 4,096
    float* vh    = ws + 34881536;      // 1,105,920
    float* vc    = ws + 35987456;      // 1,105,920
    float* S     = ws + 37093376;      // 34,560
    float* outs  = ws + 37127936;      // 131,072  (total < 37,263,104 floats = 149 MB)

    // zero padded planes (interiors overwritten)
    hipMemsetAsync(xpad,  0, (size_t)20971520*2, stream);
    hipMemsetAsync(c1pad, 0, (size_t)38535168*2, stream);

    // CNN
    apack2k<<<128, 256, 0, stream>>>(cnn_w2, apack2);
    conv1k<<<512*26, 256, 0, stream>>>(frame, cnn_w1, cnn_b1, c1pad);
    c2mfma<<<2560, 256, 0, stream>>>(c1pad, apack2, cnn_b2, xpad);

    // c1pad is dead from here on — its range is reused below
    hipMemsetAsync(hpad0, 0, (size_t)1310720*2, stream);
    hipMemsetAsync(hpad1, 0, (size_t)1310720*2, stream);
    sbasisk<<<135, 256, 0, stream>>>(S);
    apack9k<<<3456, 256, 0, stream>>>(lstm_w, apack);
    // core-weight bf16 x4 packs (2.68 MB total -> cache-resident in core blocks)
    packw4k<<<128,  256, 0, stream>>>(qw1, pq1, 256, 128);
    packw4k<<<144,  256, 0, stream>>>(qw2, pq2, 128, 288);
    packw4k<<<324,  256, 0, stream>>>(qw3, pq3, 288, 288);
    packw4k<<<2088, 256, 0, stream>>>(aw1, pa1, 1043, 512);
    packw4k<<<512,  256, 0, stream>>>(aw2, pa2, 512, 256);
    packt4k<<<1024, 256, 0, stream>>>(w_ih, pih, 256, 1024);
    packt4k<<<1024, 256, 0, stream>>>(w_hh, phh, 256, 1024);
    h0packk<<<4320, 256, 0, stream>>>(conv_h0, hpad0);
    hipMemcpyAsync(vc,  conv_c0, (size_t)16*128*540*sizeof(float), hipMemcpyDeviceToDevice, stream);
    hipMemcpyAsync(hsb, core_h0, (size_t)16*256*sizeof(float), hipMemcpyDeviceToDevice, stream);
    hipMemcpyAsync(csb, core_c0, (size_t)16*256*sizeof(float), hipMemcpyDeviceToDevice, stream);

    // software-pipelined loop: vis step t  ||  core step t-1  (33 dispatches)
    for (int t = 0; t <= T_; ++t){
        gvck<<<304, 512, 0, stream>>>(xpad, (t&1)?hpad1:hpad0, (t&1)?hpad0:hpad1,
                                      apack, lstm_b, done, vh, vc, hreA,
                                      S, pq1,qb1,pq2,qb2,pq3,qb3,
                                      pa1,ab1,pa2,ab2, pih,phh,b_ih,b_hh,
                                      reward, lact, hsb, csb, outs, t);
    }

    finalk<<<512, 64, 0, stream>>>(outs, pw, pb, vw, vb, dout);

    hipMemcpyAsync(dout + 10240,   outs + (size_t)31*B_*256, (size_t)16*256*sizeof(float), hipMemcpyDeviceToDevice, stream);
    hipMemcpyAsync(dout + 14336,   csb, (size_t)16*256*sizeof(float), hipMemcpyDeviceToDevice, stream);
    hipMemcpyAsync(dout + 18432,   vh,  (size_t)16*128*540*sizeof(float), hipMemcpyDeviceToDevice, stream);
    hipMemcpyAsync(dout + 1124352, vc,  (size_t)16*128*540*sizeof(float), hipMemcpyDeviceToDevice, stream);
}

// Round 5
// 4800.680 us; speedup vs baseline: 2.1125x; 1.0266x over previous
//
#include <hip/hip_runtime.h>
#include <math.h>

#define T_ 32
#define B_ 16
#define NA 18
#define P_ 540   // 27*20

typedef __attribute__((ext_vector_type(8)))  short short8;
typedef __attribute__((ext_vector_type(16))) float f32x16;

__device__ __forceinline__ float sigm(float x){ return 1.0f/(1.0f+expf(-x)); }
__device__ __forceinline__ unsigned short f2bf(float f){
    unsigned u = __float_as_uint(f);
    u += 0x7fff + ((u>>16)&1u);
    return (unsigned short)(u>>16);
}
__device__ __forceinline__ float bfu(unsigned short u){ return __uint_as_float(((unsigned)u)<<16); }

// ---------------- conv1: (512,3,210,160) -> c1pad bf16 [512][32][56][42], k8 s4 padH(1,1) W(2,2)
// 2 output rows per block: 12-row tile, 80 FMA per weight-load pair.
__global__ __launch_bounds__(256) void conv1k(const float* __restrict__ frame,
                                              const float* __restrict__ w,
                                              const float* __restrict__ bias,
                                              unsigned short* __restrict__ c1pad){
    __shared__ float tile[6048];  // 3ch * 12rows * 168cols
    int bid = blockIdx.x;
    int n = bid / 26, oh = (bid % 26)*2;
    int tid = threadIdx.x;
    const float* fb = frame + (size_t)n*3*210*160;
    for (int s = tid; s < 6048; s += 256){
        int col = s % 168;
        int row = (s/168) % 12;
        int ic  = s / 2016;
        int iy = oh*4 - 1 + row;
        int ix = col - 2;
        float v = 0.f;
        if (iy >= 0 && iy < 210 && ix >= 0 && ix < 160) v = fb[ic*33600 + iy*160 + ix];
        tile[s] = v;
    }
    __syncthreads();
    int oc = tid & 31, grp = tid >> 5;      // grp 0..7 -> ow = grp*5..grp*5+4
    float acc[10] = {0.f,0.f,0.f,0.f,0.f,0.f,0.f,0.f,0.f,0.f};
    const float* wb = w + oc*192;
    for (int ic=0; ic<3; ++ic){
        #pragma unroll
        for (int kh=0; kh<8; ++kh){
            const float* wr = wb + ic*64 + kh*8;
            float4 w0 = *((const float4*)wr);
            float4 w1 = *((const float4*)(wr+4));
            const float* rowA = tile + ic*2016 + kh*168 + grp*20;
            float r[24];
            *((float4*)(r+ 0)) = *((const float4*)(rowA+ 0));
            *((float4*)(r+ 4)) = *((const float4*)(rowA+ 4));
            *((float4*)(r+ 8)) = *((const float4*)(rowA+ 8));
            *((float4*)(r+12)) = *((const float4*)(rowA+12));
            *((float4*)(r+16)) = *((const float4*)(rowA+16));
            *((float4*)(r+20)) = *((const float4*)(rowA+20));
            #pragma unroll
            for (int o=0;o<5;++o){
                acc[o] += r[o*4+0]*w0.x + r[o*4+1]*w0.y + r[o*4+2]*w0.z + r[o*4+3]*w0.w
                        + r[o*4+4]*w1.x + r[o*4+5]*w1.y + r[o*4+6]*w1.z + r[o*4+7]*w1.w;
            }
            const float* rowB = rowA + 672;   // +4 input rows
            *((float4*)(r+ 0)) = *((const float4*)(rowB+ 0));
            *((float4*)(r+ 4)) = *((const float4*)(rowB+ 4));
            *((float4*)(r+ 8)) = *((const float4*)(rowB+ 8));
            *((float4*)(r+12)) = *((const float4*)(rowB+12));
            *((float4*)(r+16)) = *((const float4*)(rowB+16));
            *((float4*)(r+20)) = *((const float4*)(rowB+20));
            #pragma unroll
            for (int o=0;o<5;++o){
                acc[5+o] += r[o*4+0]*w0.x + r[o*4+1]*w0.y + r[o*4+2]*w0.z + r[o*4+3]*w0.w
                          + r[o*4+4]*w1.x + r[o*4+5]*w1.y + r[o*4+6]*w1.z + r[o*4+7]*w1.w;
            }
        }
    }
    float bi = bias[oc];
    unsigned short* ob = c1pad + ((size_t)(n*32 + oc)*56 + oh+2)*42 + 1;
    #pragma unroll
    for (int o=0;o<5;++o) ob[grp*5+o] = f2bf(acc[o] + bi);
    ob += 42;
    #pragma unroll
    for (int o=0;o<5;++o) ob[grp*5+o] = f2bf(acc[5+o] + bi);
}

// ---------------- conv2 A-pack: cnn_w2 (64,32,4,4) -> apack2[32 ic][2 mt][64 lane][8] bf16
__global__ void apack2k(const float* __restrict__ w2, unsigned short* __restrict__ ap){
    int idx = blockIdx.x*256 + threadIdx.x;
    if (idx >= 32768) return;
    int j = idx & 7;
    int lane = (idx>>3) & 63;
    int mt = (idx>>9) & 1;
    int ic = idx >> 10;
    int k = ((lane>>5)<<3) + j;          // kh*4+kw
    int oc = mt*32 + (lane & 31);
    ap[idx] = f2bf(w2[((oc*32 + ic)<<4) + k]);
}

// ---------------- conv2 MFMA: c1pad bf16 -> xre bf16 [512][540 pos][64 oc], k4 s2 padH(2,2) W(1,1)
__global__ __launch_bounds__(256) void c2mfma(const unsigned short* __restrict__ c1pad,
                                              const unsigned short* __restrict__ apack2,
                                              const float* __restrict__ bias,
                                              unsigned short* __restrict__ xre){
    __shared__ unsigned short p2[2][3072];   // [n 128][stride 24]
    __shared__ float bsm[64];
    int bid = blockIdx.x;
    int s = bid / 5;
    int n0 = (bid % 5) * 128;
    int tid = threadIdx.x;
    int wave = tid >> 6, lane = tid & 63;
    int khalf = (lane>>5) << 3;
    if (tid < 64) bsm[tid] = bias[tid];
    const unsigned short* cb = c1pad + (size_t)s*32*2352;

    int soff[8], swaddr[8];
    #pragma unroll
    for (int q=0;q<8;++q){
        int idx = q*256 + tid;
        int n = idx & 127, k = idx >> 7;
        int p = n0 + n; if (p > 539) p = 539;
        soff[q] = ((p/20)*2 + (k>>2))*42 + (p%20)*2 + (k&3);
        swaddr[q] = n*24 + k;
    }
    #pragma unroll
    for (int q=0;q<8;++q) p2[0][swaddr[q]] = cb[soff[q]];
    unsigned short rv[8];
    #pragma unroll
    for (int q=0;q<8;++q) rv[q] = cb[2352 + soff[q]];

    int mt = wave >> 1, ntb = (wave & 1) * 2;
    short8 acur = *((const short8*)(apack2 + ((size_t)mt*64 + lane)*8));
    short8 anxt;
    f32x16 acc[2];
    #pragma unroll
    for (int jj=0;jj<2;++jj)
        #pragma unroll
        for (int rg=0;rg<16;++rg) acc[jj][rg] = 0.f;
    __syncthreads();

    for (int c=0; c<32; ++c){
        int buf = c & 1;
        if (c < 31){
            #pragma unroll
            for (int q=0;q<8;++q) p2[buf^1][swaddr[q]] = rv[q];
        }
        if (c < 30){
            const unsigned short* src = cb + (size_t)(c+2)*2352;
            #pragma unroll
            for (int q=0;q<8;++q) rv[q] = src[soff[q]];
        }
        if (c < 31) anxt = *((const short8*)(apack2 + ((size_t)((c+1)*2 + mt)*64 + lane)*8));
        #pragma unroll
        for (int jj=0;jj<2;++jj){
            int n = (ntb+jj)*32 + (lane & 31);
            short8 bf = *((const short8*)(&p2[buf][n*24 + khalf]));
            acc[jj] = __builtin_amdgcn_mfma_f32_32x32x16_bf16(acur, bf, acc[jj], 0, 0, 0);
        }
        acur = anxt;
        __syncthreads();
    }
    #pragma unroll
    for (int jj=0;jj<2;++jj){
        int pos = n0 + (ntb+jj)*32 + (lane & 31);
        if (pos >= 540) continue;
        unsigned short* op = xre + ((size_t)s*540 + pos)*64;
        #pragma unroll
        for (int rg=0; rg<16; ++rg){
            int oc = mt*32 + (rg & 3) + 8*(rg>>2) + 4*(lane>>5);
            op[oc] = f2bf(acc[jj][rg] + bsm[oc]);
        }
    }
}

// ---------------- spatial basis S[540][64]
__global__ void sbasisk(float* __restrict__ S){
    int idx = blockIdx.x*256 + threadIdx.x;
    if (idx >= P_*64) return;
    int s = idx & 63, p = idx >> 6;
    int y = p/20, x = p%20;
    int u = s >> 3, v = s & 7;
    double a  = cos((double)((y+1)*(u+1)) * M_PI / 27.0);
    double bb = cos((double)((x+1)*(v+1)) * M_PI / 20.0);
    S[idx] = (float)(a*bb);
}

// ---------------- weight pack: f32 [R][C] -> bf16 [(R+3)/4][C][4]  (pad rows -> 0)
__global__ void packw4k(const float* __restrict__ in, unsigned short* __restrict__ out, int R, int C){
    int idx = blockIdx.x*256 + threadIdx.x;
    int r4cnt = (R+3)>>2;
    if (idx >= r4cnt*C*4) return;
    int j = idx & 3;
    int rc = idx >> 2;
    int c = rc % C;
    int r = (rc / C)*4 + j;
    out[idx] = (r < R) ? f2bf(in[(size_t)r*C + c]) : (unsigned short)0;
}
// ---------------- weight pack (transposed input): f32 [C][R] -> bf16 [(R+3)/4][C][4]
__global__ void packt4k(const float* __restrict__ in, unsigned short* __restrict__ out, int R, int C){
    int idx = blockIdx.x*256 + threadIdx.x;
    int r4cnt = (R+3)>>2;
    if (idx >= r4cnt*C*4) return;
    int j = idx & 3;
    int rc = idx >> 2;
    int c = rc % C;
    int r = (rc / C)*4 + j;
    out[idx] = (r < R) ? f2bf(in[(size_t)c*R + r]) : (unsigned short)0;
}

// ---------------- gates A-pack (tap-wise): lstm_w (512,192,3,3) ->
// ap[tap 9][chunk 12][16 mt][64 lane][8] bf16, K = 192 channels (no zero padding)
__global__ void apack9k(const float* __restrict__ lw, unsigned short* __restrict__ ap){
    int idx = blockIdx.x*256 + threadIdx.x;
    if (idx >= 884736) return;
    int j = idx & 7;
    int lane = (idx>>3) & 63;
    int mt = (idx>>9) & 15;
    int f  = idx >> 13;            // 0..107 = tap*12 + c
    int tap = f / 12, c = f % 12;
    int ch = c*16 + ((lane>>5)<<3) + j;
    int oc = mt*32 + (lane & 31);
    ap[idx] = f2bf(lw[(size_t)oc*1728 + ch*9 + tap]);
}

// ---------------- pack conv_h0 fp32 [b][128][540] -> h0re bf16 [b][540 pos][128 ch] (true layout)
__global__ void h0rek(const float* __restrict__ h0, unsigned short* __restrict__ h0re){
    int idx = blockIdx.x*256 + threadIdx.x;
    if (idx >= 16*128*540) return;
    int plane = idx / 540, p = idx % 540;
    int b = plane >> 7, c = plane & 127;
    h0re[((size_t)b*540 + p)*128 + c] = f2bf(h0[idx]);
}

// =====================================================================================
// gvck: ONE dispatch per t does BOTH pipeline stages concurrently:
//   blocks 0..15   : core recurrence step t-1 (critical chain -> scheduled first)
//   blocks 16..303 : vis ConvLSTM step t — B-fragments read DIRECTLY from global
//                    position-major tensors (xre / hplain / h0re): zero LDS staging,
//                    zero bank conflicts, one barrier total. Boundary pad via lane mask,
//                    done-mask skips the 8 h-chunks uniformly.
// =====================================================================================
__global__ __launch_bounds__(512) void gvck(const unsigned short* __restrict__ xre,
                                            const unsigned short* __restrict__ hrd,
                                            unsigned short* __restrict__ hwr,
                                            const unsigned short* __restrict__ h0re,
                                            const unsigned short* __restrict__ apack,
                                            const float* __restrict__ lb,
                                            const unsigned char* __restrict__ done,
                                            float* __restrict__ vh, float* __restrict__ vc,
                                            unsigned short* __restrict__ hreA,
                                            const float* __restrict__ S,
                                            const unsigned short* __restrict__ pq1, const float* __restrict__ qb1,
                                            const unsigned short* __restrict__ pq2, const float* __restrict__ qb2,
                                            const unsigned short* __restrict__ pq3, const float* __restrict__ qb3,
                                            const unsigned short* __restrict__ pa1, const float* __restrict__ ab1,
                                            const unsigned short* __restrict__ pa2, const float* __restrict__ ab2,
                                            const unsigned short* __restrict__ pih, const unsigned short* __restrict__ phh,
                                            const float* __restrict__ bih, const float* __restrict__ bhh,
                                            const float* __restrict__ reward, const int* __restrict__ lact,
                                            float* __restrict__ hsb, float* __restrict__ csb,
                                            float* __restrict__ outs,
                                            int t){
    __shared__ __align__(16) unsigned char smraw[65536];
    int bid = blockIdx.x;
    int tid = threadIdx.x;

    if (bid >= 16){
        // ---------------- vis ConvLSTM step t ----------------
        if (t >= T_) return;
        float* gsm = (float*)smraw;                    // [4][64][64] f32 (64 KB)
        int vb = bid - 16;
        int b  = vb % 16;
        int r  = vb / 16;
        int nb = r % 9;
        int mh = r / 9;
        int wave = tid >> 6, lane = tid & 63;
        int khalf = (lane>>5) << 3;
        int n0 = nb * 64;
        bool dn = done[t*B_ + b];

        const unsigned short* xb = xre + (size_t)(t*B_ + b)*540*64;
        const unsigned short* hp2 = (t==0) ? (h0re + (size_t)b*540*128)
                                           : (hrd  + (size_t)b*540*128);

        // wave -> (gate, half): mt = gate*4 + mh*2 + half
        int mt = (wave>>1)*4 + mh*2 + (wave&1);

        // per (jj, tap): source position + validity (boundary zero-pad)
        int poff[2][9]; int vmask[2][9];
        #pragma unroll
        for (int jj=0;jj<2;++jj){
            int p = n0 + jj*32 + (lane & 31); if (p > 539) p = 539;
            int y = p/20, x = p%20;
            #pragma unroll
            for (int tap=0;tap<9;++tap){
                int dy = tap/3 - 1, dx = tap%3 - 1;
                int yy = y+dy, xx = x+dx;
                vmask[jj][tap] = ((unsigned)yy < 27u) && ((unsigned)xx < 20u);
                poff[jj][tap] = yy*20 + xx;
            }
        }
        const short8 z8 = {0,0,0,0,0,0,0,0};
        f32x16 acc[2];
        #pragma unroll
        for (int jj=0;jj<2;++jj)
            #pragma unroll
            for (int rg=0;rg<16;++rg) acc[jj][rg] = 0.f;

        // x-chunks (in-ch 0..63): 4 chunks x 9 taps
        for (int c=0;c<4;++c){
            int cho = c*16 + khalf;
            #pragma unroll
            for (int tap=0;tap<9;++tap){
                short8 af = *((const short8*)(apack + ((size_t)((tap*12+c)*16 + mt)*64 + lane)*8));
                short8 b0 = vmask[0][tap] ? *((const short8*)(xb + poff[0][tap]*64 + cho)) : z8;
                short8 b1 = vmask[1][tap] ? *((const short8*)(xb + poff[1][tap]*64 + cho)) : z8;
                acc[0] = __builtin_amdgcn_mfma_f32_32x32x16_bf16(af, b0, acc[0], 0, 0, 0);
                acc[1] = __builtin_amdgcn_mfma_f32_32x32x16_bf16(af, b1, acc[1], 0, 0, 0);
            }
        }
        // h-chunks (in-ch 64..191): skipped entirely when done (h==0)
        if (!dn){
            for (int c=4;c<12;++c){
                int cho = (c-4)*16 + khalf;
                #pragma unroll
                for (int tap=0;tap<9;++tap){
                    short8 af = *((const short8*)(apack + ((size_t)((tap*12+c)*16 + mt)*64 + lane)*8));
                    short8 b0 = vmask[0][tap] ? *((const short8*)(hp2 + poff[0][tap]*128 + cho)) : z8;
                    short8 b1 = vmask[1][tap] ? *((const short8*)(hp2 + poff[1][tap]*128 + cho)) : z8;
                    acc[0] = __builtin_amdgcn_mfma_f32_32x32x16_bf16(af, b0, acc[0], 0, 0, 0);
                    acc[1] = __builtin_amdgcn_mfma_f32_32x32x16_bf16(af, b1, acc[1], 0, 0, 0);
                }
            }
        }

        // stage gates to LDS: gsm[gate][c_loc][p_loc]
        int g8 = wave >> 1, ih = wave & 1;
        #pragma unroll
        for (int j=0;j<2;++j){
            int p_loc = j*32 + (lane & 31);
            #pragma unroll
            for (int rg=0; rg<16; ++rg){
                int c_loc = ih*32 + 4*(lane>>5) + (rg & 3) + 8*(rg>>2);
                gsm[g8*4096 + c_loc*64 + p_loc] = acc[j][rg];
            }
        }
        __syncthreads();

        // fused LSTM pointwise: 512 threads x 8 elements over 64c x 64p
        {
            int p_loc = tid & 63, c0 = tid >> 6;
            int pg = n0 + p_loc;
            if (pg < 540){
                float m = dn ? 0.f : 1.f;
                #pragma unroll
                for (int e=0;e<8;++e){
                    int c_loc = c0*8 + e;
                    int cg = mh*64 + c_loc;
                    float gi = gsm[        c_loc*64 + p_loc] + lb[      cg];
                    float gf = gsm[ 4096 + c_loc*64 + p_loc] + lb[128 + cg];
                    float go = gsm[ 8192 + c_loc*64 + p_loc] + lb[256 + cg];
                    float gg = gsm[12288 + c_loc*64 + p_loc] + lb[384 + cg];
                    size_t idx = ((size_t)b*128 + cg)*540 + pg;
                    float cold = vc[idx] * m;
                    float cn = sigm(gf)*cold + sigm(gi)*tanhf(gg);
                    float hn = sigm(go)*tanhf(cn);
                    vc[idx] = cn;
                    if (t == T_-1) vh[idx] = hn;
                    unsigned short hb16 = f2bf(hn);
                    hwr[((size_t)b*540 + pg)*128 + cg] = hb16;   // true [pos][ch] for next vis
                    int flat = cg*540 + pg;                      // flat copy for core (reshape semantics)
                    int pos = (flat/2560)*20 + (flat/128)%20;
                    int ch  = flat & 127;
                    hreA[((size_t)(t*B_ + b)*540 + pos)*128 + ch] = hb16;
                }
            }
        }
        return;
    }

    // ---------------- core recurrence step tc = t-1 ----------------
    if (t == 0) return;
    int tc = t - 1;
    int b = bid;
    float* fs = (float*)smraw;
    float* hs   = fs;          // 256
    float* cs   = fs + 256;    // 256
    float* hs2  = fs + 512;    // 256
    float* q1   = fs + 768;    // 128
    float* q2   = fs + 896;    // 288
    float* q3   = fs + 1184;   // 288
    float* elog = fs + 1472;   // 4*540
    float* red  = fs + 3632;   // 32
    float* ansv = fs + 3664;   // 1056
    float* hid  = fs + 4720;   // 512
    float* cis  = fs + 5232;   // 256
    float* gb   = fs + 5488;   // 1024  (ends 6512 floats = 26 KB)

    if (tid < 256){ hs[tid] = hsb[b*256+tid]; cs[tid] = csb[b*256+tid]; }
    if (tid >= 256 && tid < 269) ansv[1043 + (tid-256)] = 0.f;   // pad rows of aw1 -> 0
    __syncthreads();

    float m = done[tc*B_+b] ? 0.f : 1.f;
    // ---- q1 = relu(hs @ qw1 + qb1)
    if (tid < 128){
        float a0=0.f,a1=0.f,a2=0.f,a3=0.f;
        for (int i4=0;i4<64;++i4){
            ushort4 w = *((const ushort4*)(pq1 + (size_t)((i4<<7)+tid)*4));
            float4 h4 = *((const float4*)(hs + i4*4));
            a0 += h4.x*bfu(w.x); a1 += h4.y*bfu(w.y);
            a2 += h4.z*bfu(w.z); a3 += h4.w*bfu(w.w);
        }
        q1[tid] = fmaxf(qb1[tid] + ((a0+a1)+(a2+a3)), 0.f);
    }
    __syncthreads();
    // ---- q2 = relu(q1 @ qw2 + qb2)
    if (tid < 288){
        float a0=0.f,a1=0.f,a2=0.f,a3=0.f;
        for (int i4=0;i4<32;++i4){
            ushort4 w = *((const ushort4*)(pq2 + (size_t)(i4*288+tid)*4));
            float4 h4 = *((const float4*)(q1 + i4*4));
            a0 += h4.x*bfu(w.x); a1 += h4.y*bfu(w.y);
            a2 += h4.z*bfu(w.z); a3 += h4.w*bfu(w.w);
        }
        q2[tid] = fmaxf(qb2[tid] + ((a0+a1)+(a2+a3)), 0.f);
    }
    __syncthreads();
    // ---- q3 = q2 @ qw3 + qb3
    if (tid < 288){
        float a0=0.f,a1=0.f,a2=0.f,a3=0.f;
        for (int i4=0;i4<72;++i4){
            ushort4 w = *((const ushort4*)(pq3 + (size_t)(i4*288+tid)*4));
            float4 h4 = *((const float4*)(q2 + i4*4));
            a0 += h4.x*bfu(w.x); a1 += h4.y*bfu(w.y);
            a2 += h4.z*bfu(w.z); a3 += h4.w*bfu(w.w);
        }
        float a = qb3[tid] + ((a0+a1)+(a2+a3));
        q3[tid] = a;
        ansv[736+tid] = a;
    }
    if (tid == 0){ float r = reward[tc*B_+b]; ansv[1024] = fminf(1.f,fmaxf(-1.f,r)); }
    if (tid >= 32 && tid < 32+NA) ansv[1025 + tid-32] = (lact[tc*B_+b] == tid-32) ? 1.f : 0.f;
    __syncthreads();

    // ---- attention logits
    const unsigned short* hrb = hreA + (size_t)(tc*B_ + b)*540*128;
    for (int idx = tid; idx < 4*P_; idx += 512){
        int qi = idx / P_, p = idx % P_;
        const unsigned short* hp = hrb + (size_t)p*128;
        uint4 hv = *((const uint4*)hp);
        const float* qv = q3 + qi*72;
        float a = __uint_as_float(hv.x<<16)*qv[0] + __uint_as_float(hv.x & 0xffff0000u)*qv[1]
                + __uint_as_float(hv.y<<16)*qv[2] + __uint_as_float(hv.y & 0xffff0000u)*qv[3]
                + __uint_as_float(hv.z<<16)*qv[4] + __uint_as_float(hv.z & 0xffff0000u)*qv[5]
                + __uint_as_float(hv.w<<16)*qv[6] + __uint_as_float(hv.w & 0xffff0000u)*qv[7];
        const float* Sp = S + p*64;
        #pragma unroll
        for (int s2=0;s2<16;++s2){
            float4 sv = *((const float4*)(Sp + 4*s2));
            a += sv.x*qv[8+4*s2] + sv.y*qv[9+4*s2] + sv.z*qv[10+4*s2] + sv.w*qv[11+4*s2];
        }
        elog[qi*P_ + p] = a;
    }
    __syncthreads();
    // ---- softmax (max, exp, sum) per query
    {
        int qi = tid >> 7, lt = tid & 127;
        float mx = -1e30f;
        for (int p = lt; p < P_; p += 128) mx = fmaxf(mx, elog[qi*P_ + p]);
        for (int off=32; off; off>>=1) mx = fmaxf(mx, __shfl_down(mx, off));
        if ((tid & 63) == 0) red[tid>>6] = mx;
        __syncthreads();
        if (tid < 4) red[16+tid] = fmaxf(red[2*tid], red[2*tid+1]);
        __syncthreads();
        mx = red[16+qi];
        float sm = 0.f;
        for (int p = lt; p < P_; p += 128){ float e = expf(elog[qi*P_ + p]-mx); elog[qi*P_ + p] = e; sm += e; }
        for (int off=32; off; off>>=1) sm += __shfl_down(sm, off);
        if ((tid & 63) == 0) red[8 + (tid>>6)] = sm;
        __syncthreads();
        if (tid < 4) red[24+tid] = red[8+2*tid] + red[8+2*tid+1];
        __syncthreads();
    }
    // ---- ans = softmax(A) @ V : vectorized, 4-lane p-split + shfl reduce
    if (tid < 240){
        int g = tid >> 2;            // 60 groups: qi 0..3 x vb 0..14 (8 channels each)
        int qi = g / 15, vb = g % 15;
        int pc = tid & 3;
        float ac[8] = {0,0,0,0,0,0,0,0};
        const unsigned short* hb8 = hrb + 8 + vb*8;
        for (int p = pc*135; p < pc*135+135; ++p){
            float e = elog[qi*P_ + p];
            uint4 hv = *((const uint4*)(hb8 + (size_t)p*128));
            ac[0] += e*__uint_as_float(hv.x<<16);
            ac[1] += e*__uint_as_float(hv.x & 0xffff0000u);
            ac[2] += e*__uint_as_float(hv.y<<16);
            ac[3] += e*__uint_as_float(hv.y & 0xffff0000u);
            ac[4] += e*__uint_as_float(hv.z<<16);
            ac[5] += e*__uint_as_float(hv.z & 0xffff0000u);
            ac[6] += e*__uint_as_float(hv.w<<16);
            ac[7] += e*__uint_as_float(hv.w & 0xffff0000u);
        }
        #pragma unroll
        for (int j=0;j<8;++j){ ac[j] += __shfl_down(ac[j],2); ac[j] += __shfl_down(ac[j],1); }
        if ((tid&3)==0){
            float inv2 = 1.f/red[24+qi];
            #pragma unroll
            for (int j=0;j<8;++j) ansv[qi*184 + vb*8 + j] = ac[j]*inv2;
        }
    } else if (tid < 496){
        int u = tid - 240;
        int g = u >> 2;              // 64 groups: qi 0..3 x vb4 0..15 (4 floats of S each)
        int qi = g >> 4, vb4 = g & 15;
        int pc = u & 3;
        float ac[4] = {0,0,0,0};
        const float* Sp = S + vb4*4;
        for (int p = pc*135; p < pc*135+135; ++p){
            float e = elog[qi*P_ + p];
            float4 sv = *((const float4*)(Sp + (size_t)p*64));
            ac[0]+=e*sv.x; ac[1]+=e*sv.y; ac[2]+=e*sv.z; ac[3]+=e*sv.w;
        }
        #pragma unroll
        for (int j=0;j<4;++j){ ac[j] += __shfl_down(ac[j],2); ac[j] += __shfl_down(ac[j],1); }
        if ((tid&3)==0){
            float inv2 = 1.f/red[24+qi];
            #pragma unroll
            for (int j=0;j<4;++j) ansv[qi*184 + 120 + vb4*4 + j] = ac[j]*inv2;
        }
    }
    __syncthreads();
    // ---- hid = relu(ansv @ aw1 + ab1)
    {
        float a0=ab1[tid], a1=0.f, a2=0.f, a3=0.f;
        for (int i4=0;i4<261;++i4){
            ushort4 w = *((const ushort4*)(pa1 + (size_t)((i4<<9)+tid)*4));
            float4 av = *((const float4*)(ansv + i4*4));
            a0 += av.x*bfu(w.x); a1 += av.y*bfu(w.y);
            a2 += av.z*bfu(w.z); a3 += av.w*bfu(w.w);
        }
        hid[tid] = fmaxf((a0+a1)+(a2+a3), 0.f);
    }
    if (tid < 256) hs2[tid] = hs[tid]*m;
    __syncthreads();
    // ---- cis = hid @ aw2 + ab2
    if (tid < 256){
        float a0=ab2[tid],a1=0.f,a2=0.f,a3=0.f;
        for (int i4=0;i4<128;++i4){
            ushort4 w = *((const ushort4*)(pa2 + (size_t)((i4<<8)+tid)*4));
            float4 hv = *((const float4*)(hid + i4*4));
            a0 += hv.x*bfu(w.x); a1 += hv.y*bfu(w.y);
            a2 += hv.z*bfu(w.z); a3 += hv.w*bfu(w.w);
        }
        cis[tid] = (a0+a1)+(a2+a3);
    }
    __syncthreads();
    // ---- gates = cis @ w_ih^T + hs2 @ w_hh^T + b
    for (int g = tid; g < 1024; g += 512){
        float a0=bih[g]+bhh[g], a1=0.f, a2=0.f, a3=0.f;
        for (int i4=0;i4<64;++i4){
            ushort4 wi = *((const ushort4*)(pih + (size_t)((i4<<10)+g)*4));
            ushort4 wh = *((const ushort4*)(phh + (size_t)((i4<<10)+g)*4));
            float4 cv = *((const float4*)(cis + i4*4));
            float4 hv = *((const float4*)(hs2 + i4*4));
            a0 += cv.x*bfu(wi.x) + hv.x*bfu(wh.x);
            a1 += cv.y*bfu(wi.y) + hv.y*bfu(wh.y);
            a2 += cv.z*bfu(wi.z) + hv.z*bfu(wh.z);
            a3 += cv.w*bfu(wi.w) + hv.w*bfu(wh.w);
        }
        gb[g] = (a0+a1)+(a2+a3);
    }
    __syncthreads();
    if (tid < 256){
        float gi = gb[tid], gf = gb[256+tid], gg = gb[512+tid], go = gb[768+tid];
        float cold = cs[tid]*m;
        float cn = sigm(gf)*cold + sigm(gi)*tanhf(gg);
        float hn = sigm(go)*tanhf(cn);
        csb[b*256+tid] = cn;
        hsb[b*256+tid] = hn;
        outs[(tc*B_+b)*256+tid] = hn;
    }
}

// ---------------- heads
__global__ __launch_bounds__(64) void finalk(const float* __restrict__ outs,
                                             const float* __restrict__ pw, const float* __restrict__ pb,
                                             const float* __restrict__ vw, const float* __restrict__ vb,
                                             float* __restrict__ dout){
    int row = blockIdx.x, tid = threadIdx.x;
    __shared__ float os[256];
    __shared__ float lg[NA];
    for (int i=tid; i<256; i+=64) os[i] = outs[row*256+i];
    __syncthreads();
    if (tid < NA){
        float a = pb[tid];
        for (int i=0;i<256;++i) a += os[i]*pw[i*NA+tid];
        lg[tid] = a;
        dout[row*NA + tid] = a;
    } else if (tid == 32){
        float a = vb[0];
        for (int i=0;i<256;++i) a += os[i]*vw[i];
        dout[9216 + row] = a;
    }
    __syncthreads();
    if (tid == 0){
        int am = 0; float bv = lg[0];
        for (int j=1;j<NA;++j) if (lg[j] > bv){ bv = lg[j]; am = j; }
        dout[9728 + row] = (float)am;
    }
}

extern "C" void kernel_launch(void* const* d_in, const int* in_sizes, int n_in,
                              void* d_out, int out_size, void* d_ws, size_t ws_size,
                              hipStream_t stream) {
    const float* frame   = (const float*)d_in[0];
    const unsigned char* done = (const unsigned char*)d_in[1];
    const int*   lact    = (const int*)d_in[2];
    const float* reward  = (const float*)d_in[3];
    const float* core_h0 = (const float*)d_in[4];
    const float* core_c0 = (const float*)d_in[5];
    const float* conv_h0 = (const float*)d_in[6];
    const float* conv_c0 = (const float*)d_in[7];
    const float* cnn_w1  = (const float*)d_in[8];
    const float* cnn_b1  = (const float*)d_in[9];
    const float* cnn_w2  = (const float*)d_in[10];
    const float* cnn_b2  = (const float*)d_in[11];
    const float* lstm_w  = (const float*)d_in[12];
    const float* lstm_b  = (const float*)d_in[13];
    const float* qw1 = (const float*)d_in[14]; const float* qb1 = (const float*)d_in[15];
    const float* qw2 = (const float*)d_in[16]; const float* qb2 = (const float*)d_in[17];
    const float* qw3 = (const float*)d_in[18]; const float* qb3 = (const float*)d_in[19];
    const float* aw1 = (const float*)d_in[20]; const float* ab1 = (const float*)d_in[21];
    const float* aw2 = (const float*)d_in[22]; const float* ab2 = (const float*)d_in[23];
    const float* w_ih = (const float*)d_in[24]; const float* w_hh = (const float*)d_in[25];
    const float* b_ih = (const float*)d_in[26]; const float* b_hh = (const float*)d_in[27];
    const float* pw = (const float*)d_in[28]; const float* pb = (const float*)d_in[29];
    const float* vw = (const float*)d_in[30]; const float* vb = (const float*)d_in[31];

    float* ws = (float*)d_ws;
    float* dout = (float*)d_out;

    // ws layout (float offsets). c1pad is transient: consumed by c2mfma, then
    // hreA/apack/weight-packs are written into that range (after c2mfma in stream order).
    unsigned short* xre    = (unsigned short*)ws;                         // 17,694,720 u16 (512*540*64)
    unsigned short* c1pad  = (unsigned short*)(ws + 10485760);            // 38,535,168 u16 (transient)
    unsigned short* hreA   = (unsigned short*)(ws + 10485760);            // 35,389,440 u16 (flat-copy layout)
    unsigned short* apack  = (unsigned short*)(ws + 28180480);            // 884,736 u16 (tap-wise)
    unsigned short* wpk    = (unsigned short*)(ws + 28966912);            // packed core weights (bf16)
    unsigned short* pq1 = wpk;            // 32768
    unsigned short* pq2 = wpk + 32768;    // 36864
    unsigned short* pq3 = wpk + 69632;    // 82944
    unsigned short* pa1 = wpk + 152576;   // 534528
    unsigned short* pa2 = wpk + 687104;   // 131072
    unsigned short* pih = wpk + 818176;   // 262144
    unsigned short* phh = wpk + 1080320;  // ends 1,342,464
    unsigned short* h0re   = (unsigned short*)(ws + 29753344);            // 1,105,920 u16 (true [pos][ch])
    unsigned short* apack2 = (unsigned short*)(ws + 30408704);            // 32,768 u16
    unsigned short* hpl0   = (unsigned short*)(ws + 30425088);            // 1,105,920 u16 (true [pos][ch])
    float* hsb   = ws + 31080448;      // 4,096
    float* csb   = ws + 31084544;      // 4,096
    unsigned short* hpl1   = (unsigned short*)(ws + 31100928);            // 1,105,920 u16
    float* vh    = ws + 34881536;      // 1,105,920
    float* vc    = ws + 35987456;      // 1,105,920
    float* S     = ws + 37093376;      // 34,560
    float* outs  = ws + 37127936;      // 131,072  (total < 37,263,104 floats = 149 MB)

    // zero padded conv1 output planes (interior overwritten)
    hipMemsetAsync(c1pad, 0, (size_t)38535168*2, stream);

    // CNN
    apack2k<<<128, 256, 0, stream>>>(cnn_w2, apack2);
    conv1k<<<512*26, 256, 0, stream>>>(frame, cnn_w1, cnn_b1, c1pad);
    c2mfma<<<2560, 256, 0, stream>>>(c1pad, apack2, cnn_b2, xre);

    // c1pad is dead from here on — its range is reused below
    sbasisk<<<135, 256, 0, stream>>>(S);
    apack9k<<<3456, 256, 0, stream>>>(lstm_w, apack);
    // core-weight bf16 x4 packs (2.68 MB total -> cache-resident in core blocks)
    packw4k<<<128,  256, 0, stream>>>(qw1, pq1, 256, 128);
    packw4k<<<144,  256, 0, stream>>>(qw2, pq2, 128, 288);
    packw4k<<<324,  256, 0, stream>>>(qw3, pq3, 288, 288);
    packw4k<<<2088, 256, 0, stream>>>(aw1, pa1, 1043, 512);
    packw4k<<<512,  256, 0, stream>>>(aw2, pa2, 512, 256);
    packt4k<<<1024, 256, 0, stream>>>(w_ih, pih, 256, 1024);
    packt4k<<<1024, 256, 0, stream>>>(w_hh, phh, 256, 1024);
    h0rek<<<4320, 256, 0, stream>>>(conv_h0, h0re);
    hipMemcpyAsync(vc,  conv_c0, (size_t)16*128*540*sizeof(float), hipMemcpyDeviceToDevice, stream);
    hipMemcpyAsync(hsb, core_h0, (size_t)16*256*sizeof(float), hipMemcpyDeviceToDevice, stream);
    hipMemcpyAsync(csb, core_c0, (size_t)16*256*sizeof(float), hipMemcpyDeviceToDevice, stream);

    // software-pipelined loop: vis step t  ||  core step t-1  (33 dispatches)
    for (int t = 0; t <= T_; ++t){
        gvck<<<304, 512, 0, stream>>>(xre,
                                      (t&1)?hpl0:hpl1, (t&1)?hpl1:hpl0, h0re,
                                      apack, lstm_b, done, vh, vc, hreA,
                                      S, pq1,qb1,pq2,qb2,pq3,qb3,
                                      pa1,ab1,pa2,ab2, pih,phh,b_ih,b_hh,
                                      reward, lact, hsb, csb, outs, t);
    }

    finalk<<<512, 64, 0, stream>>>(outs, pw, pb, vw, vb, dout);

    hipMemcpyAsync(dout + 10240,   outs + (size_t)31*B_*256, (size_t)16*256*sizeof(float), hipMemcpyDeviceToDevice, stream);
    hipMemcpyAsync(dout + 14336,   csb, (size_t)16*256*sizeof(float), hipMemcpyDeviceToDevice, stream);
    hipMemcpyAsync(dout + 18432,   vh,  (size_t)16*128*540*sizeof(float), hipMemcpyDeviceToDevice, stream);
    hipMemcpyAsync(dout + 1124352, vc,  (size_t)16*128*540*sizeof(float), hipMemcpyDeviceToDevice, stream);
}